// Round 15
// baseline (340.892 us; speedup 1.0000x reference)
//
#include <hip/hip_runtime.h>

#define B_    64
#define CIN_  3
#define HW_   64
#define HID_  128
#define K_    1024
#define H1_   31      // after conv1 (stride2 k4)
#define H2_   30      // after conv2 (stride1 k2)
#define NROWS_ 57600  // B_*H2_*H2_
#define NELEM_ 7372800

typedef __bf16 bf16_t;
typedef __attribute__((ext_vector_type(8))) __bf16 bf16x8;
typedef __attribute__((ext_vector_type(4))) float f32x4;

// ---------------- conv1: x[64,3,64,64] -> relu -> z1p[64,128,32,32] (padded)
__global__ __launch_bounds__(256) void conv1_k(const float* __restrict__ x,
    const float* __restrict__ w, const float* __restrict__ bias,
    float* __restrict__ z1p) {
  int blk = blockIdx.x, b = blk >> 7, co = blk & 127;     // grid = 64*128
  const float* wp = w + co * 48;                          // [co][ci][4][4]
  float wr[48];
  #pragma unroll
  for (int i = 0; i < 48; ++i) wr[i] = wp[i];             // uniform -> SGPRs
  const float* xb = x + (size_t)b * CIN_ * HW_ * HW_;
  float* zb = z1p + ((size_t)blk << 10);                  // 32x32 padded plane
  float bv = bias[co];
  for (int j = threadIdx.x; j < H1_ * H1_; j += 256) {
    int oh = j / H1_, ow = j % H1_;
    float acc = bv;
    #pragma unroll
    for (int ci = 0; ci < CIN_; ++ci) {
      const float* xp = xb + ci * HW_ * HW_ + (oh * 2) * HW_ + ow * 2;
      #pragma unroll
      for (int kh = 0; kh < 4; ++kh)
        #pragma unroll
        for (int kw = 0; kw < 4; ++kw)
          acc += xp[kh * HW_ + kw] * wr[ci * 16 + kh * 4 + kw];
    }
    zb[(oh << 5) + ow] = fmaxf(acc, 0.f);                 // pad never read
  }
}

// ---------------- tz: z1p fp32 [b*128][1024] -> z1t bf16 [b][1024][128] -----
__global__ __launch_bounds__(256) void tz_k(const float* __restrict__ z1p,
    bf16_t* __restrict__ z1t) {
  __shared__ bf16_t t[64 * 136];
  int b = blockIdx.x >> 4, pc = blockIdx.x & 15;          // 64-pos chunk
  int tid = threadIdx.x;
  const float4* src = (const float4*)z1p;
  #pragma unroll
  for (int s = 0; s < 8; ++s) {
    int f = s * 256 + tid;                                // 2048 f4s
    int ci = f >> 4, c16 = f & 15;
    float4 v = src[(size_t)(b * HID_ + ci) * 256 + pc * 16 + c16];
    t[(c16 * 4 + 0) * 136 + ci] = (bf16_t)v.x;
    t[(c16 * 4 + 1) * 136 + ci] = (bf16_t)v.y;
    t[(c16 * 4 + 2) * 136 + ci] = (bf16_t)v.z;
    t[(c16 * 4 + 3) * 136 + ci] = (bf16_t)v.w;
  }
  __syncthreads();
  #pragma unroll
  for (int s = 0; s < 4; ++s) {
    int f = s * 256 + tid;                                // 1024 f4s out
    int pos = f >> 4, c16 = f & 15;
    *(float4*)&z1t[((size_t)b * 1024 + pc * 64 + pos) * 128 + c16 * 8] =
        *(float4*)&t[pos * 136 + c16 * 8];
  }
}

// ---------------- wprep: bf16 weight transposes -----------------------------
// wc2[t][co][ci] = ew2[co][ci][t]; wd1[t][co][ci] = dw1[ci][co][3-t]
// wt2[n][tap*128+ci] = dw2[ci][co][tapoff], n = co*4+ph*2+pw (n>=12 zero)
__global__ __launch_bounds__(256) void wprep_k(const float* __restrict__ ew2,
    const float* __restrict__ dw1, const float* __restrict__ dw2,
    bf16_t* __restrict__ wc2, bf16_t* __restrict__ wd1,
    bf16_t* __restrict__ wt2) {
  int id = blockIdx.x * 256 + threadIdx.x;                // grid 256 -> 65536
  int t = id >> 14, co = (id >> 7) & 127, ci = id & 127;
  wc2[id] = (bf16_t)ew2[(co * 128 + ci) * 4 + t];
  wd1[id] = (bf16_t)dw1[(ci * 128 + co) * 4 + (3 - t)];
  if (id < 8192) {
    int n = id >> 9, k = id & 511;
    int tap = k >> 7, c = k & 127;
    if (n < 12) {
      int nco = n >> 2, ph = (n >> 1) & 1, pw = n & 1;
      int off = (tap >> 1) * 8 + (tap & 1) * 2;           // 0,2,8,10
      wt2[id] = (bf16_t)dw2[c * 48 + nco * 16 + ph * 4 + pw + off];
    } else {
      wt2[id] = (bf16_t)0.f;
    }
  }
}

// ---------------- conv2 (MFMA, B in LDS): z1t -> relu -> z + zbuf -----------
__global__ __launch_bounds__(256, 2) void conv2m_k(const bf16_t* __restrict__ z1t,
    const bf16_t* __restrict__ wc2, const float* __restrict__ bias,
    float* __restrict__ z, ushort* __restrict__ zbuf) {
  __shared__ __align__(16) bf16_t as_[98 * 136];          // rows m+off, off<=33
  __shared__ __align__(16) bf16_t bs_[128 * 136];
  int blk = blockIdx.x;                                   // 64*15
  int b = blk / 15, rt = blk % 15;
  int tid = threadIdx.x, wv = tid >> 6, ln = tid & 63;
  const float4* src = (const float4*)(z1t + ((size_t)b * 1024 + rt * 64) * 128);
  #pragma unroll
  for (int s = 0; s < 7; ++s) {
    int f = s * 256 + tid;                                // 98*16 = 1568 f4s
    if (f < 1568) {
      int lp = f >> 4, c16 = f & 15;                      // max row 993 < 1024
      *(float4*)&as_[lp * 136 + c16 * 8] = src[f];
    }
  }
  int m = wv * 16 + (ln & 15), q = ln >> 4;
  f32x4 acc8[8];
  #pragma unroll
  for (int c = 0; c < 8; ++c) acc8[c] = (f32x4){0.f, 0.f, 0.f, 0.f};
  const float4* w4 = (const float4*)wc2;
  #pragma unroll
  for (int t = 0; t < 4; ++t) {
    __syncthreads();                                      // bs_ reuse (+A 1st)
    #pragma unroll
    for (int s = 0; s < 8; ++s) {
      int f = s * 256 + tid;                              // 2048 f4s
      int co = f >> 4, c16 = f & 15;
      *(float4*)&bs_[co * 136 + c16 * 8] = w4[t * 2048 + f];
    }
    __syncthreads();
    int off = (t >> 1) * 32 + (t & 1);                    // tap offset in pos
    bf16x8 af[4];
    #pragma unroll
    for (int kk = 0; kk < 4; ++kk)
      af[kk] = *(const bf16x8*)&as_[(m + off) * 136 + kk * 32 + q * 8];
    #pragma unroll
    for (int cot = 0; cot < 8; ++cot) {
      #pragma unroll
      for (int kk = 0; kk < 4; ++kk) {
        bf16x8 bf = *(const bf16x8*)&bs_[(cot * 16 + (ln & 15)) * 136 +
                                         kk * 32 + q * 8];
        acc8[cot] = __builtin_amdgcn_mfma_f32_16x16x32_bf16(af[kk], bf,
                                                            acc8[cot], 0, 0, 0);
      }
    }
  }
  #pragma unroll
  for (int cot = 0; cot < 8; ++cot) {
    int co = cot * 16 + (ln & 15);
    float bv = bias[co];
    #pragma unroll
    for (int r = 0; r < 4; ++r) {
      int mo = wv * 16 + q * 4 + r;
      int ocol = mo & 31;
      if (ocol < 30) {
        int orow = rt * 2 + (mo >> 5);                    // always < 30
        float v = fmaxf(acc8[cot][r] + bv, 0.f);
        size_t idx = (size_t)(b * HID_ + co) * 900 + orow * 30 + ocol;
        z[idx] = v;
        bf16_t h = (bf16_t)v;
        zbuf[idx] = *(ushort*)&h;                         // fused cvt for vq1
      }
    }
  }
}

// ---------------- prep: cb -> bf16 copy + bf16-consistent norms + zeros -----
__global__ __launch_bounds__(256) void prep_k(const float* __restrict__ cb,
    bf16_t* __restrict__ cbb, float* __restrict__ cnorm,
    unsigned* __restrict__ hist, float* __restrict__ sse) {
  int k = blockIdx.x * 256 + threadIdx.x;
  if (k < K_) {
    float s0 = 0.f;
    for (int d = 0; d < HID_; d += 4) {
      float4 v = *(const float4*)&cb[k * HID_ + d];
      bf16_t t[4] = {(bf16_t)v.x, (bf16_t)v.y, (bf16_t)v.z, (bf16_t)v.w};
      *(ushort4*)&((ushort*)cbb)[k * HID_ + d] = *(ushort4*)t;
      float f0 = (float)t[0], f1 = (float)t[1];
      float f2 = (float)t[2], f3 = (float)t[3];
      s0 += f0 * f0 + f1 * f1 + f2 * f2 + f3 * f3;
    }
    cnorm[k] = s0;
    hist[k] = 0u;
  }
  if (k == 0 && blockIdx.x == 0) *sse = 0.f;
}

__global__ __launch_bounds__(256) void zero_k(float4* __restrict__ p, int n4) {
  int i = blockIdx.x * 256 + threadIdx.x;
  if (i < n4) p[i] = make_float4(0.f, 0.f, 0.f, 0.f);
}

// ---------------- VQ phase 1 (MFMA): 64 rows x 1024 codes + hist ------------
// r13 shape (M=64, 900 blocks — r14's M=128/450 regressed: grid sub-capacity)
// + cheap argmin (r13's u64 pack was the dominant VALU load: 27% VALUBusy)
// + 16-lane shuffle reduce (drops the 8 KB red buffer: 51 KB LDS -> 3 blk/CU).
__global__ __launch_bounds__(256, 2) void vq1_k(const bf16_t* __restrict__ zb,
    const bf16_t* __restrict__ cbb, const float* __restrict__ cnorm,
    int* __restrict__ idxArr, unsigned* __restrict__ hist) {
  __shared__ __align__(16) bf16_t zs[64 * 136];           // 17 KB
  __shared__ __align__(16) bf16_t cbs[128 * 136];         // 34 KB
  int n0 = blockIdx.x * 64;                               // 900 blocks
  int tid = threadIdx.x;
  int wv = tid >> 6, ln = tid & 63;
  {
    const float4* zg4 = (const float4*)(zb + (size_t)n0 * HID_);
    #pragma unroll
    for (int s = 0; s < 4; ++s) {
      int f = s * 256 + tid;
      int row = f >> 4, seg = f & 15;
      *(float4*)&zs[row * 136 + seg * 8] = zg4[f];
    }
  }
  __syncthreads();
  bf16x8 afr[4];
  #pragma unroll
  for (int kk = 0; kk < 4; ++kk)
    afr[kk] = *(const bf16x8*)&zs[(wv * 16 + (ln & 15)) * 136 + kk * 32 +
                                  (ln >> 4) * 8];
  float best[4] = {3.4e38f, 3.4e38f, 3.4e38f, 3.4e38f};
  int bidx[4] = {0, 0, 0, 0};
  const float4* cg4 = (const float4*)cbb;
  for (int c0 = 0; c0 < K_; c0 += 128) {
    __syncthreads();
    #pragma unroll
    for (int s = 0; s < 8; ++s) {
      int f = s * 256 + tid;
      int code = f >> 4, seg = f & 15;
      *(float4*)&cbs[code * 136 + seg * 8] = cg4[(c0 + code) * 16 + seg];
    }
    __syncthreads();
    #pragma unroll 2
    for (int t = 0; t < 8; ++t) {
      int code = c0 + t * 16 + (ln & 15);
      float cn = cnorm[code];
      f32x4 acc = {0.f, 0.f, 0.f, 0.f};
      #pragma unroll
      for (int kk = 0; kk < 4; ++kk) {
        bf16x8 bfr = *(const bf16x8*)&cbs[(t * 16 + (ln & 15)) * 136 +
                                          kk * 32 + (ln >> 4) * 8];
        acc = __builtin_amdgcn_mfma_f32_16x16x32_bf16(afr[kk], bfr, acc,
                                                      0, 0, 0);
      }
      #pragma unroll
      for (int r = 0; r < 4; ++r) {
        float d = cn - 2.f * acc[r];
        if (d < best[r]) { best[r] = d; bidx[r] = code; } // strict <: first k
      }
    }
  }
  // reduce across the 16 lanes sharing q = ln>>4 (xor of low 4 lane bits)
  #pragma unroll
  for (int r = 0; r < 4; ++r) {
    float bv = best[r];
    int bi = bidx[r];
    #pragma unroll
    for (int o = 8; o > 0; o >>= 1) {
      float ob = __shfl_xor(bv, o, 64);
      int oi = __shfl_xor(bi, o, 64);
      if (ob < bv || (ob == bv && oi < bi)) { bv = ob; bi = oi; }
    }
    best[r] = bv;
    bidx[r] = bi;
  }
  if ((ln & 15) == 0) {
    int q = ln >> 4;
    #pragma unroll
    for (int r = 0; r < 4; ++r) {
      int row = n0 + wv * 16 + q * 4 + r;
      idxArr[row] = bidx[r];
      atomicAdd(&hist[bidx[r]], 1u);
    }
  }
}

// ---------------- tq: gather cbb rows -> qt bf16 [b][pos][ci], coalesced ----
__global__ __launch_bounds__(256) void tq_k(const bf16_t* __restrict__ cbb,
    const int* __restrict__ idxArr, ushort* __restrict__ qt) {
  __shared__ ushort t[60 * 128];                          // 15 KB
  int b = blockIdx.x / 15, st = blockIdx.x % 15;          // 60-s tile
  int tid = threadIdx.x;
  int s0 = st * 60;
  #pragma unroll
  for (int it = 0; it < 8; ++it) {
    int task = it * 256 + tid;                            // sc*128 + c
    if (task < 1920) {
      int sc = task >> 7, c = task & 127;
      int f = b * 115200 + c * 900 + s0 + sc * 4;
      int n = f >> 7, d = f & 127;                        // d%4==0, no wrap
      int k = idxArr[n];
      ushort4 v = *(const ushort4*)((const ushort*)cbb + k * 128 + d);
      t[(sc * 4 + 0) * 128 + c] = v.x;
      t[(sc * 4 + 1) * 128 + c] = v.y;
      t[(sc * 4 + 2) * 128 + c] = v.z;
      t[(sc * 4 + 3) * 128 + c] = v.w;
    }
  }
  __syncthreads();
  #pragma unroll
  for (int it = 0; it < 4; ++it) {
    int task = it * 256 + tid;                            // sl*16 + c16
    if (task < 960) {
      int sl = task >> 4, c16 = task & 15;
      int s = s0 + sl;
      int h = s / 30, w = s - h * 30;
      int p = (h + 1) * 32 + (w + 1);
      *(uint4*)&qt[((size_t)(b * 1024 + p)) * 128 + c16 * 8] =
          *(uint4*)&t[sl * 128 + c16 * 8];
    }
  }
}

// ---------------- sse: fp32 SSE, 8 float4/thread, wave-shuffle reduce -------
__global__ __launch_bounds__(256) void sse_k(const float4* __restrict__ z4,
    const float* __restrict__ cb, const int* __restrict__ idxArr,
    float* __restrict__ sse) {
  int base = blockIdx.x * 2048 + threadIdx.x;             // 900 blocks exact
  float se = 0.f;
  #pragma unroll
  for (int it = 0; it < 8; ++it) {
    int i = base + it * 256;
    int f = i * 4;
    int n = f >> 7, d = f & 127;
    int k = idxArr[n];
    float4 zv = z4[i];
    float4 cv = *(const float4*)&cb[k * 128 + d];
    float dx = cv.x - zv.x, dy = cv.y - zv.y;
    float dz = cv.z - zv.z, dw = cv.w - zv.w;
    se += dx * dx + dy * dy + dz * dz + dw * dw;
  }
  #pragma unroll
  for (int o = 32; o > 0; o >>= 1) se += __shfl_down(se, o, 64);
  __shared__ float red[4];
  if ((threadIdx.x & 63) == 0) red[threadIdx.x >> 6] = se;
  __syncthreads();
  if (threadIdx.x == 0)
    atomicAdd(sse, red[0] + red[1] + red[2] + red[3]);
}

// ---------------- convT1 (MFMA, B in LDS): qt -> relu -> yt bf16 ------------
__global__ __launch_bounds__(256, 2) void convt1m_k(const bf16_t* __restrict__ qt,
    const bf16_t* __restrict__ wd1, const float* __restrict__ bias,
    ushort* __restrict__ yt) {
  __shared__ __align__(16) bf16_t as_[98 * 136];
  __shared__ __align__(16) bf16_t bs_[128 * 136];
  int blk = blockIdx.x;                                   // 64*16
  int b = blk >> 4, rt = blk & 15;
  int tid = threadIdx.x, wv = tid >> 6, ln = tid & 63;
  const float4* src = (const float4*)(qt + (size_t)b * 1024 * 128);
  #pragma unroll
  for (int s = 0; s < 7; ++s) {
    int f = s * 256 + tid;                                // 1568 f4s
    if (f < 1568) {
      int lp = f >> 4, c16 = f & 15;
      int gr = rt * 64 + lp;
      if (gr > 1023) gr = 1023;                           // rt=15 guard
      *(float4*)&as_[lp * 136 + c16 * 8] = src[gr * 16 + c16];
    }
  }
  int m = wv * 16 + (ln & 15), q = ln >> 4;
  f32x4 acc8[8];
  #pragma unroll
  for (int c = 0; c < 8; ++c) acc8[c] = (f32x4){0.f, 0.f, 0.f, 0.f};
  const float4* w4 = (const float4*)wd1;
  #pragma unroll
  for (int t = 0; t < 4; ++t) {
    __syncthreads();
    #pragma unroll
    for (int s = 0; s < 8; ++s) {
      int f = s * 256 + tid;
      int co = f >> 4, c16 = f & 15;
      *(float4*)&bs_[co * 136 + c16 * 8] = w4[t * 2048 + f];
    }
    __syncthreads();
    int off = (t >> 1) * 32 + (t & 1);
    bf16x8 af[4];
    #pragma unroll
    for (int kk = 0; kk < 4; ++kk)
      af[kk] = *(const bf16x8*)&as_[(m + off) * 136 + kk * 32 + q * 8];
    #pragma unroll
    for (int cot = 0; cot < 8; ++cot) {
      #pragma unroll
      for (int kk = 0; kk < 4; ++kk) {
        bf16x8 bf = *(const bf16x8*)&bs_[(cot * 16 + (ln & 15)) * 136 +
                                         kk * 32 + q * 8];
        acc8[cot] = __builtin_amdgcn_mfma_f32_16x16x32_bf16(af[kk], bf,
                                                            acc8[cot], 0, 0, 0);
      }
    }
  }
  #pragma unroll
  for (int cot = 0; cot < 8; ++cot) {
    int co = cot * 16 + (ln & 15);
    float bv = bias[co];
    #pragma unroll
    for (int r = 0; r < 4; ++r) {
      int mo = wv * 16 + q * 4 + r;
      int orow = rt * 2 + (mo >> 5), ocol = mo & 31;
      if (orow < 31 && ocol < 31) {
        float v = fmaxf(acc8[cot][r] + bv, 0.f);
        bf16_t h = (bf16_t)v;
        yt[((size_t)b * 1156 + (orow + 1) * 34 + (ocol + 1)) * 128 + co] =
            *(ushort*)&h;
      }
    }
  }
}

// ---------------- convT2 (MFMA): yt -> out fp32 ------------------------------
__global__ __launch_bounds__(256, 2) void convt2m_k(const bf16_t* __restrict__ yt,
    const bf16_t* __restrict__ wt2, const float* __restrict__ bias,
    float* __restrict__ out) {
  __shared__ __align__(16) bf16_t as_[128 * 136];         // 34.8 KB
  int b = blockIdx.x >> 4, rt = blockIdx.x & 15;          // grid = 64*16
  int tid = threadIdx.x, wv = tid >> 6, ln = tid & 63;
  const float4* src = (const float4*)(yt + ((size_t)b * 1156 + rt * 68) * 128);
  #pragma unroll
  for (int s = 0; s < 8; ++s) {
    int f = s * 256 + tid;
    int lp = f >> 4, c16 = f & 15;
    *(float4*)&as_[lp * 136 + c16 * 8] = src[f];
  }
  __syncthreads();
  int mloc = wv * 16 + (ln & 15), q = ln >> 4;
  int qh = mloc >> 5, qw = mloc & 31;                     // local quadrant pos
  int base = (qh + 1) * 34 + qw + 1;                      // in staged window
  f32x4 acc = {0.f, 0.f, 0.f, 0.f};
  #pragma unroll
  for (int kc = 0; kc < 16; ++kc) {
    int tap = kc >> 2;
    int toff = (tap & 1) + (tap >> 1) * 34;               // 0,1,34,35
    bf16x8 af = *(const bf16x8*)&as_[(base - toff) * 136 +
                                     (kc & 3) * 32 + q * 8];
    bf16x8 bf = *(const bf16x8*)&wt2[(size_t)(ln & 15) * 512 + kc * 32 + q * 8];
    acc = __builtin_amdgcn_mfma_f32_16x16x32_bf16(af, bf, acc, 0, 0, 0);
  }
  __syncthreads();                                        // as_ reads done
  float* bb = (float*)as_;                                // bounce: 64x16 f32
  #pragma unroll
  for (int r = 0; r < 4; ++r)
    bb[(wv * 16 + q * 4 + r) * 16 + (ln & 15)] = acc[r];
  __syncthreads();
  if (tid < 192) {
    int row_id = tid >> 4;                                // co*4 + ohoff
    int co = row_id >> 2, ohoff = row_id & 3;
    int qhl = ohoff >> 1, ph = ohoff & 1;
    float bv = bias[co];
    int ow0 = (tid & 15) * 4;
    float tmp[4];
    #pragma unroll
    for (int e = 0; e < 4; ++e) {
      int ow = ow0 + e;
      tmp[e] = bb[(qhl * 32 + (ow >> 1)) * 16 + co * 4 + ph * 2 + (ow & 1)]
               + bv;
    }
    *(float4*)&out[((size_t)(b * 3 + co)) * 4096 + (rt * 4 + ohoff) * 64 + ow0]
        = *(float4*)tmp;
  }
}

// ---------------- finalize: loss + perplexity -------------------------------
__global__ __launch_bounds__(256) void fin_k(const unsigned* __restrict__ hist,
    const float* __restrict__ sse, float* __restrict__ out) {
  __shared__ float red[256];
  float e = 0.f;
  for (int k = threadIdx.x; k < K_; k += 256) {
    float p = (float)hist[k] * (1.0f / (float)NROWS_);
    e += p * logf(p + 1e-10f);
  }
  red[threadIdx.x] = e;
  __syncthreads();
  #pragma unroll
  for (int t = 128; t > 0; t >>= 1) {
    if (threadIdx.x < t) red[threadIdx.x] += red[threadIdx.x + t];
    __syncthreads();
  }
  if (threadIdx.x == 0) {
    out[786432] = 1.25f * (*sse) * (1.0f / (float)NELEM_);
    out[786433] = expf(-red[0]);
  }
}

extern "C" void kernel_launch(void* const* d_in, const int* in_sizes, int n_in,
                              void* d_out, int out_size, void* d_ws,
                              size_t ws_size, hipStream_t stream) {
  (void)in_sizes; (void)n_in; (void)out_size; (void)ws_size;
  const float* x   = (const float*)d_in[0];
  const float* ew1 = (const float*)d_in[1];
  const float* eb1 = (const float*)d_in[2];
  const float* ew2 = (const float*)d_in[3];
  const float* eb2 = (const float*)d_in[4];
  const float* cb  = (const float*)d_in[5];
  const float* dw1 = (const float*)d_in[6];
  const float* db1 = (const float*)d_in[7];
  const float* dw2 = (const float*)d_in[8];
  const float* db2 = (const float*)d_in[9];
  float* out = (float*)d_out;
  char* ws = (char*)d_ws;

  // ws layout (~97.5 MB, aliased by liveness):
  //  [0, 35,684,352)            z1p fp32 (conv1->tz) then yt bf16 18.94 MB
  //  [35,684,352, 65,175,552)   z fp32 (conv2m->sse)
  //  [65,175,552, 81,985,536)   z1t bf16 +slack (tz->conv2m) then qt bf16
  //  [81,985,536, 96,731,136)   zbuf bf16 (conv2m->vq1)
  //  [96,731,136 ..)            cbb | wc2 | wd1 | idxArr | hist | cnorm | sse | wt2
  float*    z1p   = (float*)(ws);
  ushort*   yt    = (ushort*)(ws);
  float*    z     = (float*)(ws + 35684352);
  bf16_t*   z1t   = (bf16_t*)(ws + 65175552);
  bf16_t*   qt    = (bf16_t*)(ws + 65175552);
  ushort*   zbuf  = (ushort*)(ws + 81985536);
  bf16_t*   cbb   = (bf16_t*)(ws + 96731136);
  bf16_t*   wc2   = (bf16_t*)(ws + 96993280);
  bf16_t*   wd1   = (bf16_t*)(ws + 97124352);
  int*      idxArr= (int*)(ws + 97255424);
  unsigned* hist  = (unsigned*)(ws + 97485824);
  float*    cnorm = (float*)(ws + 97489920);
  float*    sse   = (float*)(ws + 97494016);
  bf16_t*   wt2   = (bf16_t*)(ws + 97497088);

  conv1_k<<<dim3(B_ * HID_), dim3(256), 0, stream>>>(x, ew1, eb1, z1p);
  tz_k<<<dim3(1024), dim3(256), 0, stream>>>(z1p, z1t);
  wprep_k<<<dim3(256), dim3(256), 0, stream>>>(ew2, dw1, dw2, wc2, wd1, wt2);
  conv2m_k<<<dim3(960), dim3(256), 0, stream>>>(z1t, wc2, eb2, z, zbuf);
  prep_k<<<dim3(4), dim3(256), 0, stream>>>(cb, cbb, cnorm, hist, sse);
  vq1_k<<<dim3(900), dim3(256), 0, stream>>>((const bf16_t*)zbuf, cbb, cnorm,
                                             idxArr, hist);
  zero_k<<<dim3(4624), dim3(256), 0, stream>>>((float4*)yt, 1183744);
  zero_k<<<dim3(4104), dim3(256), 0, stream>>>((float4*)qt, 1050624);
  tq_k<<<dim3(960), dim3(256), 0, stream>>>(cbb, idxArr, (ushort*)qt);
  sse_k<<<dim3(900), dim3(256), 0, stream>>>((const float4*)z, cb, idxArr,
                                             sse);
  convt1m_k<<<dim3(1024), dim3(256), 0, stream>>>(qt, wd1, db1, yt);
  convt2m_k<<<dim3(1024), dim3(256), 0, stream>>>((const bf16_t*)yt, wt2, db2,
                                                  out);
  fin_k<<<dim3(1), dim3(256), 0, stream>>>(hist, sse, out);
}

// Round 16
// 317.659 us; speedup vs baseline: 1.0731x; 1.0731x over previous
//
#include <hip/hip_runtime.h>

#define B_    64
#define CIN_  3
#define HW_   64
#define HID_  128
#define K_    1024
#define H1_   31      // after conv1 (stride2 k4)
#define H2_   30      // after conv2 (stride1 k2)
#define NROWS_ 57600  // B_*H2_*H2_
#define NELEM_ 7372800

typedef __bf16 bf16_t;
typedef __attribute__((ext_vector_type(8))) __bf16 bf16x8;
typedef __attribute__((ext_vector_type(4))) float f32x4;

// ---------------- conv1: x[64,3,64,64] -> relu -> z1p[64,128,32,32] (padded)
__global__ __launch_bounds__(256) void conv1_k(const float* __restrict__ x,
    const float* __restrict__ w, const float* __restrict__ bias,
    float* __restrict__ z1p) {
  int blk = blockIdx.x, b = blk >> 7, co = blk & 127;     // grid = 64*128
  const float* wp = w + co * 48;                          // [co][ci][4][4]
  float wr[48];
  #pragma unroll
  for (int i = 0; i < 48; ++i) wr[i] = wp[i];             // uniform -> SGPRs
  const float* xb = x + (size_t)b * CIN_ * HW_ * HW_;
  float* zb = z1p + ((size_t)blk << 10);                  // 32x32 padded plane
  float bv = bias[co];
  for (int j = threadIdx.x; j < H1_ * H1_; j += 256) {
    int oh = j / H1_, ow = j % H1_;
    float acc = bv;
    #pragma unroll
    for (int ci = 0; ci < CIN_; ++ci) {
      const float* xp = xb + ci * HW_ * HW_ + (oh * 2) * HW_ + ow * 2;
      #pragma unroll
      for (int kh = 0; kh < 4; ++kh)
        #pragma unroll
        for (int kw = 0; kw < 4; ++kw)
          acc += xp[kh * HW_ + kw] * wr[ci * 16 + kh * 4 + kw];
    }
    zb[(oh << 5) + ow] = fmaxf(acc, 0.f);                 // pad never read
  }
}

// ---------------- tz: z1p fp32 [b*128][1024] -> z1t bf16 [b][1024][128] -----
__global__ __launch_bounds__(256) void tz_k(const float* __restrict__ z1p,
    bf16_t* __restrict__ z1t) {
  __shared__ bf16_t t[64 * 136];
  int b = blockIdx.x >> 4, pc = blockIdx.x & 15;          // 64-pos chunk
  int tid = threadIdx.x;
  const float4* src = (const float4*)z1p;
  #pragma unroll
  for (int s = 0; s < 8; ++s) {
    int f = s * 256 + tid;                                // 2048 f4s
    int ci = f >> 4, c16 = f & 15;
    float4 v = src[(size_t)(b * HID_ + ci) * 256 + pc * 16 + c16];
    t[(c16 * 4 + 0) * 136 + ci] = (bf16_t)v.x;
    t[(c16 * 4 + 1) * 136 + ci] = (bf16_t)v.y;
    t[(c16 * 4 + 2) * 136 + ci] = (bf16_t)v.z;
    t[(c16 * 4 + 3) * 136 + ci] = (bf16_t)v.w;
  }
  __syncthreads();
  #pragma unroll
  for (int s = 0; s < 4; ++s) {
    int f = s * 256 + tid;                                // 1024 f4s out
    int pos = f >> 4, c16 = f & 15;
    *(float4*)&z1t[((size_t)b * 1024 + pc * 64 + pos) * 128 + c16 * 8] =
        *(float4*)&t[pos * 136 + c16 * 8];
  }
}

// ---------------- wprep: bf16 weight transposes -----------------------------
// wc2[t][co][ci] = ew2[co][ci][t]; wd1[t][co][ci] = dw1[ci][co][3-t]
// wt2[n][tap*128+ci] = dw2[ci][co][tapoff], n = co*4+ph*2+pw (n>=12 zero)
__global__ __launch_bounds__(256) void wprep_k(const float* __restrict__ ew2,
    const float* __restrict__ dw1, const float* __restrict__ dw2,
    bf16_t* __restrict__ wc2, bf16_t* __restrict__ wd1,
    bf16_t* __restrict__ wt2) {
  int id = blockIdx.x * 256 + threadIdx.x;                // grid 256 -> 65536
  int t = id >> 14, co = (id >> 7) & 127, ci = id & 127;
  wc2[id] = (bf16_t)ew2[(co * 128 + ci) * 4 + t];
  wd1[id] = (bf16_t)dw1[(ci * 128 + co) * 4 + (3 - t)];
  if (id < 8192) {
    int n = id >> 9, k = id & 511;
    int tap = k >> 7, c = k & 127;
    if (n < 12) {
      int nco = n >> 2, ph = (n >> 1) & 1, pw = n & 1;
      int off = (tap >> 1) * 8 + (tap & 1) * 2;           // 0,2,8,10
      wt2[id] = (bf16_t)dw2[c * 48 + nco * 16 + ph * 4 + pw + off];
    } else {
      wt2[id] = (bf16_t)0.f;
    }
  }
}

// ---------------- conv2 (MFMA, B in LDS): z1t -> relu -> z + zbuf -----------
__global__ __launch_bounds__(256, 2) void conv2m_k(const bf16_t* __restrict__ z1t,
    const bf16_t* __restrict__ wc2, const float* __restrict__ bias,
    float* __restrict__ z, ushort* __restrict__ zbuf) {
  __shared__ __align__(16) bf16_t as_[98 * 136];          // rows m+off, off<=33
  __shared__ __align__(16) bf16_t bs_[128 * 136];
  int blk = blockIdx.x;                                   // 64*15
  int b = blk / 15, rt = blk % 15;
  int tid = threadIdx.x, wv = tid >> 6, ln = tid & 63;
  const float4* src = (const float4*)(z1t + ((size_t)b * 1024 + rt * 64) * 128);
  #pragma unroll
  for (int s = 0; s < 7; ++s) {
    int f = s * 256 + tid;                                // 98*16 = 1568 f4s
    if (f < 1568) {
      int lp = f >> 4, c16 = f & 15;                      // max row 993 < 1024
      *(float4*)&as_[lp * 136 + c16 * 8] = src[f];
    }
  }
  int m = wv * 16 + (ln & 15), q = ln >> 4;
  f32x4 acc8[8];
  #pragma unroll
  for (int c = 0; c < 8; ++c) acc8[c] = (f32x4){0.f, 0.f, 0.f, 0.f};
  const float4* w4 = (const float4*)wc2;
  #pragma unroll
  for (int t = 0; t < 4; ++t) {
    __syncthreads();                                      // bs_ reuse (+A 1st)
    #pragma unroll
    for (int s = 0; s < 8; ++s) {
      int f = s * 256 + tid;                              // 2048 f4s
      int co = f >> 4, c16 = f & 15;
      *(float4*)&bs_[co * 136 + c16 * 8] = w4[t * 2048 + f];
    }
    __syncthreads();
    int off = (t >> 1) * 32 + (t & 1);                    // tap offset in pos
    bf16x8 af[4];
    #pragma unroll
    for (int kk = 0; kk < 4; ++kk)
      af[kk] = *(const bf16x8*)&as_[(m + off) * 136 + kk * 32 + q * 8];
    #pragma unroll
    for (int cot = 0; cot < 8; ++cot) {
      #pragma unroll
      for (int kk = 0; kk < 4; ++kk) {
        bf16x8 bf = *(const bf16x8*)&bs_[(cot * 16 + (ln & 15)) * 136 +
                                         kk * 32 + q * 8];
        acc8[cot] = __builtin_amdgcn_mfma_f32_16x16x32_bf16(af[kk], bf,
                                                            acc8[cot], 0, 0, 0);
      }
    }
  }
  #pragma unroll
  for (int cot = 0; cot < 8; ++cot) {
    int co = cot * 16 + (ln & 15);
    float bv = bias[co];
    #pragma unroll
    for (int r = 0; r < 4; ++r) {
      int mo = wv * 16 + q * 4 + r;
      int ocol = mo & 31;
      if (ocol < 30) {
        int orow = rt * 2 + (mo >> 5);                    // always < 30
        float v = fmaxf(acc8[cot][r] + bv, 0.f);
        size_t idx = (size_t)(b * HID_ + co) * 900 + orow * 30 + ocol;
        z[idx] = v;
        bf16_t h = (bf16_t)v;
        zbuf[idx] = *(ushort*)&h;                         // fused cvt for vq1
      }
    }
  }
}

// ---------------- prep: cb -> bf16 copy + bf16-consistent norms + zeros -----
__global__ __launch_bounds__(256) void prep_k(const float* __restrict__ cb,
    bf16_t* __restrict__ cbb, float* __restrict__ cnorm,
    unsigned* __restrict__ hist, float* __restrict__ sse) {
  int k = blockIdx.x * 256 + threadIdx.x;
  if (k < K_) {
    float s0 = 0.f;
    for (int d = 0; d < HID_; d += 4) {
      float4 v = *(const float4*)&cb[k * HID_ + d];
      bf16_t t[4] = {(bf16_t)v.x, (bf16_t)v.y, (bf16_t)v.z, (bf16_t)v.w};
      *(ushort4*)&((ushort*)cbb)[k * HID_ + d] = *(ushort4*)t;
      float f0 = (float)t[0], f1 = (float)t[1];
      float f2 = (float)t[2], f3 = (float)t[3];
      s0 += f0 * f0 + f1 * f1 + f2 * f2 + f3 * f3;
    }
    cnorm[k] = s0;
    hist[k] = 0u;
  }
  if (k == 0 && blockIdx.x == 0) *sse = 0.f;
}

__global__ __launch_bounds__(256) void zero_k(float4* __restrict__ p, int n4) {
  int i = blockIdx.x * 256 + threadIdx.x;
  if (i < n4) p[i] = make_float4(0.f, 0.f, 0.f, 0.f);
}

// ---------------- VQ phase 1 (MFMA): 64 rows x 1024 codes + hist ------------
// Exact r13 structure (measured 64.7 us: u64 monotone pack + LDS red buffer,
// M=64, 900 blocks) — r14 (M=128) and r15 (cheap argmin, VGPR 88->68) both
// regressed: the u64 VALU overlapped stall, and register headroom was being
// used to hoist cnorm loads. One delta vs r13: cnorm cached in LDS (4 KB,
// loaded once) so the per-t lookup is a ds_read, not a divergent L2 load.
__global__ __launch_bounds__(256, 2) void vq1_k(const bf16_t* __restrict__ zb,
    const bf16_t* __restrict__ cbb, const float* __restrict__ cnorm,
    int* __restrict__ idxArr, unsigned* __restrict__ hist) {
  __shared__ __align__(16) bf16_t zs[64 * 136];           // 17 KB
  __shared__ __align__(16) bf16_t cbs[128 * 136];         // 34 KB
  __shared__ unsigned long long red[64 * 16];             // 8 KB
  __shared__ float cns[K_];                               // 4 KB
  int n0 = blockIdx.x * 64;                               // 900 blocks
  int tid = threadIdx.x;
  int wv = tid >> 6, ln = tid & 63;
  {
    const float4* zg4 = (const float4*)(zb + (size_t)n0 * HID_);
    #pragma unroll
    for (int s = 0; s < 4; ++s) {
      int f = s * 256 + tid;
      int row = f >> 4, seg = f & 15;
      *(float4*)&zs[row * 136 + seg * 8] = zg4[f];
    }
    ((float4*)cns)[tid] = ((const float4*)cnorm)[tid];    // 1024 floats once
  }
  __syncthreads();
  bf16x8 afr[4];
  #pragma unroll
  for (int kk = 0; kk < 4; ++kk)
    afr[kk] = *(const bf16x8*)&zs[(wv * 16 + (ln & 15)) * 136 + kk * 32 +
                                  (ln >> 4) * 8];
  unsigned long long best[4] = {~0ull, ~0ull, ~0ull, ~0ull};
  const float4* cg4 = (const float4*)cbb;
  for (int c0 = 0; c0 < K_; c0 += 128) {
    __syncthreads();
    #pragma unroll
    for (int s = 0; s < 8; ++s) {
      int f = s * 256 + tid;
      int code = f >> 4, seg = f & 15;
      *(float4*)&cbs[code * 136 + seg * 8] = cg4[(c0 + code) * 16 + seg];
    }
    __syncthreads();
    #pragma unroll 2
    for (int t = 0; t < 8; ++t) {
      f32x4 acc = {0.f, 0.f, 0.f, 0.f};
      #pragma unroll
      for (int kk = 0; kk < 4; ++kk) {
        bf16x8 bfr = *(const bf16x8*)&cbs[(t * 16 + (ln & 15)) * 136 +
                                          kk * 32 + (ln >> 4) * 8];
        acc = __builtin_amdgcn_mfma_f32_16x16x32_bf16(afr[kk], bfr, acc,
                                                      0, 0, 0);
      }
      int code = c0 + t * 16 + (ln & 15);
      float cn = cns[code];                               // LDS, ~broadcast
      #pragma unroll
      for (int r = 0; r < 4; ++r) {
        float dist = cn - 2.f * acc[r];
        unsigned u = __float_as_uint(dist);
        u = (u & 0x80000000u) ? ~u : (u | 0x80000000u);   // monotone map
        unsigned long long p = ((unsigned long long)u << 32) | (unsigned)code;
        if (p < best[r]) best[r] = p;                     // tie -> smaller k
      }
    }
  }
  __syncthreads();
  #pragma unroll
  for (int r = 0; r < 4; ++r)
    red[(wv * 16 + (ln >> 4) * 4 + r) * 16 + (ln & 15)] = best[r];
  __syncthreads();
  if (tid < 64) {
    unsigned long long b = ~0ull;
    #pragma unroll
    for (int c = 0; c < 16; ++c) {
      unsigned long long p = red[tid * 16 + c];
      if (p < b) b = p;
    }
    int bi = (int)(b & 0xffffffffu);
    idxArr[n0 + tid] = bi;
    atomicAdd(&hist[bi], 1u);                             // hist fused here
  }
}

// ---------------- tq: gather cbb rows -> qt bf16 [b][pos][ci], coalesced ----
__global__ __launch_bounds__(256) void tq_k(const bf16_t* __restrict__ cbb,
    const int* __restrict__ idxArr, ushort* __restrict__ qt) {
  __shared__ ushort t[60 * 128];                          // 15 KB
  int b = blockIdx.x / 15, st = blockIdx.x % 15;          // 60-s tile
  int tid = threadIdx.x;
  int s0 = st * 60;
  #pragma unroll
  for (int it = 0; it < 8; ++it) {
    int task = it * 256 + tid;                            // sc*128 + c
    if (task < 1920) {
      int sc = task >> 7, c = task & 127;
      int f = b * 115200 + c * 900 + s0 + sc * 4;
      int n = f >> 7, d = f & 127;                        // d%4==0, no wrap
      int k = idxArr[n];
      ushort4 v = *(const ushort4*)((const ushort*)cbb + k * 128 + d);
      t[(sc * 4 + 0) * 128 + c] = v.x;
      t[(sc * 4 + 1) * 128 + c] = v.y;
      t[(sc * 4 + 2) * 128 + c] = v.z;
      t[(sc * 4 + 3) * 128 + c] = v.w;
    }
  }
  __syncthreads();
  #pragma unroll
  for (int it = 0; it < 4; ++it) {
    int task = it * 256 + tid;                            // sl*16 + c16
    if (task < 960) {
      int sl = task >> 4, c16 = task & 15;
      int s = s0 + sl;
      int h = s / 30, w = s - h * 30;
      int p = (h + 1) * 32 + (w + 1);
      *(uint4*)&qt[((size_t)(b * 1024 + p)) * 128 + c16 * 8] =
          *(uint4*)&t[sl * 128 + c16 * 8];
    }
  }
}

// ---------------- sse: fp32 SSE, 8 float4/thread, wave-shuffle reduce -------
__global__ __launch_bounds__(256) void sse_k(const float4* __restrict__ z4,
    const float* __restrict__ cb, const int* __restrict__ idxArr,
    float* __restrict__ sse) {
  int base = blockIdx.x * 2048 + threadIdx.x;             // 900 blocks exact
  float se = 0.f;
  #pragma unroll
  for (int it = 0; it < 8; ++it) {
    int i = base + it * 256;
    int f = i * 4;
    int n = f >> 7, d = f & 127;
    int k = idxArr[n];
    float4 zv = z4[i];
    float4 cv = *(const float4*)&cb[k * 128 + d];
    float dx = cv.x - zv.x, dy = cv.y - zv.y;
    float dz = cv.z - zv.z, dw = cv.w - zv.w;
    se += dx * dx + dy * dy + dz * dz + dw * dw;
  }
  #pragma unroll
  for (int o = 32; o > 0; o >>= 1) se += __shfl_down(se, o, 64);
  __shared__ float red[4];
  if ((threadIdx.x & 63) == 0) red[threadIdx.x >> 6] = se;
  __syncthreads();
  if (threadIdx.x == 0)
    atomicAdd(sse, red[0] + red[1] + red[2] + red[3]);
}

// ---------------- convT1 (MFMA, B in LDS): qt -> relu -> yt bf16 ------------
__global__ __launch_bounds__(256, 2) void convt1m_k(const bf16_t* __restrict__ qt,
    const bf16_t* __restrict__ wd1, const float* __restrict__ bias,
    ushort* __restrict__ yt) {
  __shared__ __align__(16) bf16_t as_[98 * 136];
  __shared__ __align__(16) bf16_t bs_[128 * 136];
  int blk = blockIdx.x;                                   // 64*16
  int b = blk >> 4, rt = blk & 15;
  int tid = threadIdx.x, wv = tid >> 6, ln = tid & 63;
  const float4* src = (const float4*)(qt + (size_t)b * 1024 * 128);
  #pragma unroll
  for (int s = 0; s < 7; ++s) {
    int f = s * 256 + tid;                                // 1568 f4s
    if (f < 1568) {
      int lp = f >> 4, c16 = f & 15;
      int gr = rt * 64 + lp;
      if (gr > 1023) gr = 1023;                           // rt=15 guard
      *(float4*)&as_[lp * 136 + c16 * 8] = src[gr * 16 + c16];
    }
  }
  int m = wv * 16 + (ln & 15), q = ln >> 4;
  f32x4 acc8[8];
  #pragma unroll
  for (int c = 0; c < 8; ++c) acc8[c] = (f32x4){0.f, 0.f, 0.f, 0.f};
  const float4* w4 = (const float4*)wd1;
  #pragma unroll
  for (int t = 0; t < 4; ++t) {
    __syncthreads();
    #pragma unroll
    for (int s = 0; s < 8; ++s) {
      int f = s * 256 + tid;
      int co = f >> 4, c16 = f & 15;
      *(float4*)&bs_[co * 136 + c16 * 8] = w4[t * 2048 + f];
    }
    __syncthreads();
    int off = (t >> 1) * 32 + (t & 1);
    bf16x8 af[4];
    #pragma unroll
    for (int kk = 0; kk < 4; ++kk)
      af[kk] = *(const bf16x8*)&as_[(m + off) * 136 + kk * 32 + q * 8];
    #pragma unroll
    for (int cot = 0; cot < 8; ++cot) {
      #pragma unroll
      for (int kk = 0; kk < 4; ++kk) {
        bf16x8 bf = *(const bf16x8*)&bs_[(cot * 16 + (ln & 15)) * 136 +
                                         kk * 32 + q * 8];
        acc8[cot] = __builtin_amdgcn_mfma_f32_16x16x32_bf16(af[kk], bf,
                                                            acc8[cot], 0, 0, 0);
      }
    }
  }
  #pragma unroll
  for (int cot = 0; cot < 8; ++cot) {
    int co = cot * 16 + (ln & 15);
    float bv = bias[co];
    #pragma unroll
    for (int r = 0; r < 4; ++r) {
      int mo = wv * 16 + q * 4 + r;
      int orow = rt * 2 + (mo >> 5), ocol = mo & 31;
      if (orow < 31 && ocol < 31) {
        float v = fmaxf(acc8[cot][r] + bv, 0.f);
        bf16_t h = (bf16_t)v;
        yt[((size_t)b * 1156 + (orow + 1) * 34 + (ocol + 1)) * 128 + co] =
            *(ushort*)&h;
      }
    }
  }
}

// ---------------- convT2 (MFMA): yt -> out fp32 ------------------------------
__global__ __launch_bounds__(256, 2) void convt2m_k(const bf16_t* __restrict__ yt,
    const bf16_t* __restrict__ wt2, const float* __restrict__ bias,
    float* __restrict__ out) {
  __shared__ __align__(16) bf16_t as_[128 * 136];         // 34.8 KB
  int b = blockIdx.x >> 4, rt = blockIdx.x & 15;          // grid = 64*16
  int tid = threadIdx.x, wv = tid >> 6, ln = tid & 63;
  const float4* src = (const float4*)(yt + ((size_t)b * 1156 + rt * 68) * 128);
  #pragma unroll
  for (int s = 0; s < 8; ++s) {
    int f = s * 256 + tid;
    int lp = f >> 4, c16 = f & 15;
    *(float4*)&as_[lp * 136 + c16 * 8] = src[f];
  }
  __syncthreads();
  int mloc = wv * 16 + (ln & 15), q = ln >> 4;
  int qh = mloc >> 5, qw = mloc & 31;                     // local quadrant pos
  int base = (qh + 1) * 34 + qw + 1;                      // in staged window
  f32x4 acc = {0.f, 0.f, 0.f, 0.f};
  #pragma unroll
  for (int kc = 0; kc < 16; ++kc) {
    int tap = kc >> 2;
    int toff = (tap & 1) + (tap >> 1) * 34;               // 0,1,34,35
    bf16x8 af = *(const bf16x8*)&as_[(base - toff) * 136 +
                                     (kc & 3) * 32 + q * 8];
    bf16x8 bf = *(const bf16x8*)&wt2[(size_t)(ln & 15) * 512 + kc * 32 + q * 8];
    acc = __builtin_amdgcn_mfma_f32_16x16x32_bf16(af, bf, acc, 0, 0, 0);
  }
  __syncthreads();                                        // as_ reads done
  float* bb = (float*)as_;                                // bounce: 64x16 f32
  #pragma unroll
  for (int r = 0; r < 4; ++r)
    bb[(wv * 16 + q * 4 + r) * 16 + (ln & 15)] = acc[r];
  __syncthreads();
  if (tid < 192) {
    int row_id = tid >> 4;                                // co*4 + ohoff
    int co = row_id >> 2, ohoff = row_id & 3;
    int qhl = ohoff >> 1, ph = ohoff & 1;
    float bv = bias[co];
    int ow0 = (tid & 15) * 4;
    float tmp[4];
    #pragma unroll
    for (int e = 0; e < 4; ++e) {
      int ow = ow0 + e;
      tmp[e] = bb[(qhl * 32 + (ow >> 1)) * 16 + co * 4 + ph * 2 + (ow & 1)]
               + bv;
    }
    *(float4*)&out[((size_t)(b * 3 + co)) * 4096 + (rt * 4 + ohoff) * 64 + ow0]
        = *(float4*)tmp;
  }
}

// ---------------- finalize: loss + perplexity -------------------------------
__global__ __launch_bounds__(256) void fin_k(const unsigned* __restrict__ hist,
    const float* __restrict__ sse, float* __restrict__ out) {
  __shared__ float red[256];
  float e = 0.f;
  for (int k = threadIdx.x; k < K_; k += 256) {
    float p = (float)hist[k] * (1.0f / (float)NROWS_);
    e += p * logf(p + 1e-10f);
  }
  red[threadIdx.x] = e;
  __syncthreads();
  #pragma unroll
  for (int t = 128; t > 0; t >>= 1) {
    if (threadIdx.x < t) red[threadIdx.x] += red[threadIdx.x + t];
    __syncthreads();
  }
  if (threadIdx.x == 0) {
    out[786432] = 1.25f * (*sse) * (1.0f / (float)NELEM_);
    out[786433] = expf(-red[0]);
  }
}

extern "C" void kernel_launch(void* const* d_in, const int* in_sizes, int n_in,
                              void* d_out, int out_size, void* d_ws,
                              size_t ws_size, hipStream_t stream) {
  (void)in_sizes; (void)n_in; (void)out_size; (void)ws_size;
  const float* x   = (const float*)d_in[0];
  const float* ew1 = (const float*)d_in[1];
  const float* eb1 = (const float*)d_in[2];
  const float* ew2 = (const float*)d_in[3];
  const float* eb2 = (const float*)d_in[4];
  const float* cb  = (const float*)d_in[5];
  const float* dw1 = (const float*)d_in[6];
  const float* db1 = (const float*)d_in[7];
  const float* dw2 = (const float*)d_in[8];
  const float* db2 = (const float*)d_in[9];
  float* out = (float*)d_out;
  char* ws = (char*)d_ws;

  // ws layout (~97.5 MB, aliased by liveness):
  //  [0, 35,684,352)            z1p fp32 (conv1->tz) then yt bf16 18.94 MB
  //  [35,684,352, 65,175,552)   z fp32 (conv2m->sse)
  //  [65,175,552, 81,985,536)   z1t bf16 +slack (tz->conv2m) then qt bf16
  //  [81,985,536, 96,731,136)   zbuf bf16 (conv2m->vq1)
  //  [96,731,136 ..)            cbb | wc2 | wd1 | idxArr | hist | cnorm | sse | wt2
  float*    z1p   = (float*)(ws);
  ushort*   yt    = (ushort*)(ws);
  float*    z     = (float*)(ws + 35684352);
  bf16_t*   z1t   = (bf16_t*)(ws + 65175552);
  bf16_t*   qt    = (bf16_t*)(ws + 65175552);
  ushort*   zbuf  = (ushort*)(ws + 81985536);
  bf16_t*   cbb   = (bf16_t*)(ws + 96731136);
  bf16_t*   wc2   = (bf16_t*)(ws + 96993280);
  bf16_t*   wd1   = (bf16_t*)(ws + 97124352);
  int*      idxArr= (int*)(ws + 97255424);
  unsigned* hist  = (unsigned*)(ws + 97485824);
  float*    cnorm = (float*)(ws + 97489920);
  float*    sse   = (float*)(ws + 97494016);
  bf16_t*   wt2   = (bf16_t*)(ws + 97497088);

  conv1_k<<<dim3(B_ * HID_), dim3(256), 0, stream>>>(x, ew1, eb1, z1p);
  tz_k<<<dim3(1024), dim3(256), 0, stream>>>(z1p, z1t);
  wprep_k<<<dim3(256), dim3(256), 0, stream>>>(ew2, dw1, dw2, wc2, wd1, wt2);
  conv2m_k<<<dim3(960), dim3(256), 0, stream>>>(z1t, wc2, eb2, z, zbuf);
  prep_k<<<dim3(4), dim3(256), 0, stream>>>(cb, cbb, cnorm, hist, sse);
  vq1_k<<<dim3(900), dim3(256), 0, stream>>>((const bf16_t*)zbuf, cbb, cnorm,
                                             idxArr, hist);
  zero_k<<<dim3(4624), dim3(256), 0, stream>>>((float4*)yt, 1183744);
  zero_k<<<dim3(4104), dim3(256), 0, stream>>>((float4*)qt, 1050624);
  tq_k<<<dim3(960), dim3(256), 0, stream>>>(cbb, idxArr, (ushort*)qt);
  sse_k<<<dim3(900), dim3(256), 0, stream>>>((const float4*)z, cb, idxArr,
                                             sse);
  convt1m_k<<<dim3(1024), dim3(256), 0, stream>>>(qt, wd1, db1, yt);
  convt2m_k<<<dim3(1024), dim3(256), 0, stream>>>((const bf16_t*)yt, wt2, db2,
                                                  out);
  fin_k<<<dim3(1), dim3(256), 0, stream>>>(hist, sse, out);
}

// Round 17
// 270.800 us; speedup vs baseline: 1.2588x; 1.1730x over previous
//
#include <hip/hip_runtime.h>

#define B_    64
#define CIN_  3
#define HW_   64
#define HID_  128
#define K_    1024
#define H1_   31      // after conv1 (stride2 k4)
#define H2_   30      // after conv2 (stride1 k2)
#define NROWS_ 57600  // B_*H2_*H2_
#define NELEM_ 7372800

typedef __bf16 bf16_t;
typedef __attribute__((ext_vector_type(8))) __bf16 bf16x8;
typedef __attribute__((ext_vector_type(4))) float f32x4;

// ---------------- wprep: all weight transposes + codebook prep --------------
// wc2[t][co][ci] = ew2[co][ci][t]; wd1[t][co][ci] = dw1[ci][co][3-t]
// wt2[n][tap*128+ci] = dw2[ci][co][tapoff], n = co*4+ph*2+pw (n>=12 zero)
// wc1[co][k64] = ew1[co][k] for k<48 else 0 (k = ci*16+kh*4+kw)
// + cb -> cbb bf16, cnorm (bf16-consistent), hist=0, sse=0   (was prep_k)
__global__ __launch_bounds__(256) void wprep_k(const float* __restrict__ ew1,
    const float* __restrict__ ew2, const float* __restrict__ dw1,
    const float* __restrict__ dw2, const float* __restrict__ cb,
    bf16_t* __restrict__ wc1, bf16_t* __restrict__ wc2,
    bf16_t* __restrict__ wd1, bf16_t* __restrict__ wt2,
    bf16_t* __restrict__ cbb, float* __restrict__ cnorm,
    unsigned* __restrict__ hist, float* __restrict__ sse) {
  int id = blockIdx.x * 256 + threadIdx.x;                // grid 256 -> 65536
  int t = id >> 14, co = (id >> 7) & 127, ci = id & 127;
  wc2[id] = (bf16_t)ew2[(co * 128 + ci) * 4 + t];
  wd1[id] = (bf16_t)dw1[(ci * 128 + co) * 4 + (3 - t)];
  if (id < 8192) {
    int n = id >> 9, k = id & 511;
    int tap = k >> 7, c = k & 127;
    if (n < 12) {
      int nco = n >> 2, ph = (n >> 1) & 1, pw = n & 1;
      int off = (tap >> 1) * 8 + (tap & 1) * 2;           // 0,2,8,10
      wt2[id] = (bf16_t)dw2[c * 48 + nco * 16 + ph * 4 + pw + off];
    } else {
      wt2[id] = (bf16_t)0.f;
    }
    int c1 = id >> 6, k1 = id & 63;                       // wc1
    wc1[id] = (bf16_t)(k1 < 48 ? ew1[c1 * 48 + k1] : 0.f);
  }
  if (id < K_) {
    float s0 = 0.f;
    for (int d = 0; d < HID_; d += 4) {
      float4 v = *(const float4*)&cb[id * HID_ + d];
      bf16_t tt[4] = {(bf16_t)v.x, (bf16_t)v.y, (bf16_t)v.z, (bf16_t)v.w};
      *(ushort4*)&((ushort*)cbb)[id * HID_ + d] = *(ushort4*)tt;
      float f0 = (float)tt[0], f1 = (float)tt[1];
      float f2 = (float)tt[2], f3 = (float)tt[3];
      s0 += f0 * f0 + f1 * f1 + f2 * f2 + f3 * f3;
    }
    cnorm[id] = s0;
    hist[id] = 0u;
  }
  if (id == 0) *sse = 0.f;
}

// ---------------- conv1 (MFMA, fused transpose): x -> relu -> z1t bf16 ------
// Implicit GEMM: M=64 pos (2 out rows), N=128 co, K=64 (48 taps + pad).
// Replaces scalar conv1_k + tz_k (z1p fp32 round-trip eliminated).
// Invalid pos (col 31 / row 31) left unwritten: garbage feeds only conv2m's
// discarded outputs (same contract tz_k had with z1p's poison pad).
__global__ __launch_bounds__(256, 2) void conv1m_k(const float* __restrict__ x,
    const bf16_t* __restrict__ wc1, const float* __restrict__ bias,
    ushort* __restrict__ z1t) {
  __shared__ __align__(16) bf16_t as_[64 * 72];           // 9 KB
  __shared__ __align__(16) bf16_t bs_[128 * 72];          // 18 KB
  int b = blockIdx.x >> 4, rt = blockIdx.x & 15;          // grid = 64*16
  int tid = threadIdx.x, wv = tid >> 6, ln = tid & 63;
  const float* xb = x + (size_t)b * 12288;
  #pragma unroll
  for (int it = 0; it < 16; ++it) {
    int e = it * 256 + tid;                               // 4096 A entries
    int p = e >> 6, k = e & 63;
    float v = 0.f;
    if (k < 48) {
      int ci = k >> 4, kh = (k >> 2) & 3, kw = k & 3;
      int row = 2 * rt + (p >> 5); if (row > 30) row = 30; // clamp: discarded
      int col = p & 31;            if (col > 30) col = 30;
      v = xb[ci * 4096 + (2 * row + kh) * 64 + 2 * col + kw];
    }
    as_[p * 72 + k] = (bf16_t)v;
  }
  {
    const float4* wg = (const float4*)wc1;
    #pragma unroll
    for (int it = 0; it < 4; ++it) {
      int fi = it * 256 + tid;                            // 1024 f4s
      int co = fi >> 3, k8 = fi & 7;
      *(float4*)&bs_[co * 72 + k8 * 8] = wg[fi];
    }
  }
  __syncthreads();
  int q = ln >> 4, l = ln & 15;
  f32x4 acc8[8];
  #pragma unroll
  for (int c = 0; c < 8; ++c) acc8[c] = (f32x4){0.f, 0.f, 0.f, 0.f};
  bf16x8 af[2];
  #pragma unroll
  for (int kk = 0; kk < 2; ++kk)
    af[kk] = *(const bf16x8*)&as_[(wv * 16 + l) * 72 + kk * 32 + q * 8];
  #pragma unroll
  for (int cot = 0; cot < 8; ++cot) {
    #pragma unroll
    for (int kk = 0; kk < 2; ++kk) {
      bf16x8 bf = *(const bf16x8*)&bs_[(cot * 16 + l) * 72 + kk * 32 + q * 8];
      acc8[cot] = __builtin_amdgcn_mfma_f32_16x16x32_bf16(af[kk], bf,
                                                          acc8[cot], 0, 0, 0);
    }
  }
  #pragma unroll
  for (int cot = 0; cot < 8; ++cot) {
    int co = cot * 16 + l;
    float bv = bias[co];
    #pragma unroll
    for (int r = 0; r < 4; ++r) {
      int pos = wv * 16 + q * 4 + r;
      int prow = 2 * rt + (pos >> 5), pcol = pos & 31;
      if (prow < 31 && pcol < 31) {
        float v = fmaxf(acc8[cot][r] + bv, 0.f);
        bf16_t h = (bf16_t)v;
        z1t[((size_t)(b * 1024 + prow * 32 + pcol)) * 128 + co] = *(ushort*)&h;
      }
    }
  }
}

// ---------------- conv2 (MFMA, B in LDS): z1t -> relu -> z + zbuf -----------
__global__ __launch_bounds__(256, 2) void conv2m_k(const bf16_t* __restrict__ z1t,
    const bf16_t* __restrict__ wc2, const float* __restrict__ bias,
    float* __restrict__ z, ushort* __restrict__ zbuf) {
  __shared__ __align__(16) bf16_t as_[98 * 136];          // rows m+off, off<=33
  __shared__ __align__(16) bf16_t bs_[128 * 136];
  int blk = blockIdx.x;                                   // 64*15
  int b = blk / 15, rt = blk % 15;
  int tid = threadIdx.x, wv = tid >> 6, ln = tid & 63;
  const float4* src = (const float4*)(z1t + ((size_t)b * 1024 + rt * 64) * 128);
  #pragma unroll
  for (int s = 0; s < 7; ++s) {
    int f = s * 256 + tid;                                // 98*16 = 1568 f4s
    if (f < 1568) {
      int lp = f >> 4, c16 = f & 15;                      // max row 993 < 1024
      *(float4*)&as_[lp * 136 + c16 * 8] = src[f];
    }
  }
  int m = wv * 16 + (ln & 15), q = ln >> 4;
  f32x4 acc8[8];
  #pragma unroll
  for (int c = 0; c < 8; ++c) acc8[c] = (f32x4){0.f, 0.f, 0.f, 0.f};
  const float4* w4 = (const float4*)wc2;
  #pragma unroll
  for (int t = 0; t < 4; ++t) {
    __syncthreads();                                      // bs_ reuse (+A 1st)
    #pragma unroll
    for (int s = 0; s < 8; ++s) {
      int f = s * 256 + tid;                              // 2048 f4s
      int co = f >> 4, c16 = f & 15;
      *(float4*)&bs_[co * 136 + c16 * 8] = w4[t * 2048 + f];
    }
    __syncthreads();
    int off = (t >> 1) * 32 + (t & 1);                    // tap offset in pos
    bf16x8 af[4];
    #pragma unroll
    for (int kk = 0; kk < 4; ++kk)
      af[kk] = *(const bf16x8*)&as_[(m + off) * 136 + kk * 32 + q * 8];
    #pragma unroll
    for (int cot = 0; cot < 8; ++cot) {
      #pragma unroll
      for (int kk = 0; kk < 4; ++kk) {
        bf16x8 bf = *(const bf16x8*)&bs_[(cot * 16 + (ln & 15)) * 136 +
                                         kk * 32 + q * 8];
        acc8[cot] = __builtin_amdgcn_mfma_f32_16x16x32_bf16(af[kk], bf,
                                                            acc8[cot], 0, 0, 0);
      }
    }
  }
  #pragma unroll
  for (int cot = 0; cot < 8; ++cot) {
    int co = cot * 16 + (ln & 15);
    float bv = bias[co];
    #pragma unroll
    for (int r = 0; r < 4; ++r) {
      int mo = wv * 16 + q * 4 + r;
      int ocol = mo & 31;
      if (ocol < 30) {
        int orow = rt * 2 + (mo >> 5);                    // always < 30
        float v = fmaxf(acc8[cot][r] + bv, 0.f);
        size_t idx = (size_t)(b * HID_ + co) * 900 + orow * 30 + ocol;
        z[idx] = v;
        bf16_t h = (bf16_t)v;
        zbuf[idx] = *(ushort*)&h;                         // fused cvt for vq1
      }
    }
  }
}

__global__ __launch_bounds__(256) void zero_k(float4* __restrict__ p, int n4) {
  int i = blockIdx.x * 256 + threadIdx.x;
  if (i < n4) p[i] = make_float4(0.f, 0.f, 0.f, 0.f);
}

// ---------------- VQ phase 1 (MFMA): 64 rows x 1024 codes + hist ------------
// r13 structure + cnorm in LDS (r16, measured 62.8-63.2 us).
__global__ __launch_bounds__(256, 2) void vq1_k(const bf16_t* __restrict__ zb,
    const bf16_t* __restrict__ cbb, const float* __restrict__ cnorm,
    int* __restrict__ idxArr, unsigned* __restrict__ hist) {
  __shared__ __align__(16) bf16_t zs[64 * 136];           // 17 KB
  __shared__ __align__(16) bf16_t cbs[128 * 136];         // 34 KB
  __shared__ unsigned long long red[64 * 16];             // 8 KB
  __shared__ float cns[K_];                               // 4 KB
  int n0 = blockIdx.x * 64;                               // 900 blocks
  int tid = threadIdx.x;
  int wv = tid >> 6, ln = tid & 63;
  {
    const float4* zg4 = (const float4*)(zb + (size_t)n0 * HID_);
    #pragma unroll
    for (int s = 0; s < 4; ++s) {
      int f = s * 256 + tid;
      int row = f >> 4, seg = f & 15;
      *(float4*)&zs[row * 136 + seg * 8] = zg4[f];
    }
    ((float4*)cns)[tid] = ((const float4*)cnorm)[tid];    // 1024 floats once
  }
  __syncthreads();
  bf16x8 afr[4];
  #pragma unroll
  for (int kk = 0; kk < 4; ++kk)
    afr[kk] = *(const bf16x8*)&zs[(wv * 16 + (ln & 15)) * 136 + kk * 32 +
                                  (ln >> 4) * 8];
  unsigned long long best[4] = {~0ull, ~0ull, ~0ull, ~0ull};
  const float4* cg4 = (const float4*)cbb;
  for (int c0 = 0; c0 < K_; c0 += 128) {
    __syncthreads();
    #pragma unroll
    for (int s = 0; s < 8; ++s) {
      int f = s * 256 + tid;
      int code = f >> 4, seg = f & 15;
      *(float4*)&cbs[code * 136 + seg * 8] = cg4[(c0 + code) * 16 + seg];
    }
    __syncthreads();
    #pragma unroll 2
    for (int t = 0; t < 8; ++t) {
      f32x4 acc = {0.f, 0.f, 0.f, 0.f};
      #pragma unroll
      for (int kk = 0; kk < 4; ++kk) {
        bf16x8 bfr = *(const bf16x8*)&cbs[(t * 16 + (ln & 15)) * 136 +
                                          kk * 32 + (ln >> 4) * 8];
        acc = __builtin_amdgcn_mfma_f32_16x16x32_bf16(afr[kk], bfr, acc,
                                                      0, 0, 0);
      }
      int code = c0 + t * 16 + (ln & 15);
      float cn = cns[code];                               // LDS, ~broadcast
      #pragma unroll
      for (int r = 0; r < 4; ++r) {
        float dist = cn - 2.f * acc[r];
        unsigned u = __float_as_uint(dist);
        u = (u & 0x80000000u) ? ~u : (u | 0x80000000u);   // monotone map
        unsigned long long p = ((unsigned long long)u << 32) | (unsigned)code;
        if (p < best[r]) best[r] = p;                     // tie -> smaller k
      }
    }
  }
  __syncthreads();
  #pragma unroll
  for (int r = 0; r < 4; ++r)
    red[(wv * 16 + (ln >> 4) * 4 + r) * 16 + (ln & 15)] = best[r];
  __syncthreads();
  if (tid < 64) {
    unsigned long long b = ~0ull;
    #pragma unroll
    for (int c = 0; c < 16; ++c) {
      unsigned long long p = red[tid * 16 + c];
      if (p < b) b = p;
    }
    int bi = (int)(b & 0xffffffffu);
    idxArr[n0 + tid] = bi;
    atomicAdd(&hist[bi], 1u);                             // hist fused here
  }
}

// ---------------- tq: gather cbb rows -> qt bf16 [b][pos][ci], coalesced ----
__global__ __launch_bounds__(256) void tq_k(const bf16_t* __restrict__ cbb,
    const int* __restrict__ idxArr, ushort* __restrict__ qt) {
  __shared__ ushort t[60 * 128];                          // 15 KB
  int b = blockIdx.x / 15, st = blockIdx.x % 15;          // 60-s tile
  int tid = threadIdx.x;
  int s0 = st * 60;
  #pragma unroll
  for (int it = 0; it < 8; ++it) {
    int task = it * 256 + tid;                            // sc*128 + c
    if (task < 1920) {
      int sc = task >> 7, c = task & 127;
      int f = b * 115200 + c * 900 + s0 + sc * 4;
      int n = f >> 7, d = f & 127;                        // d%4==0, no wrap
      int k = idxArr[n];
      ushort4 v = *(const ushort4*)((const ushort*)cbb + k * 128 + d);
      t[(sc * 4 + 0) * 128 + c] = v.x;
      t[(sc * 4 + 1) * 128 + c] = v.y;
      t[(sc * 4 + 2) * 128 + c] = v.z;
      t[(sc * 4 + 3) * 128 + c] = v.w;
    }
  }
  __syncthreads();
  #pragma unroll
  for (int it = 0; it < 4; ++it) {
    int task = it * 256 + tid;                            // sl*16 + c16
    if (task < 960) {
      int sl = task >> 4, c16 = task & 15;
      int s = s0 + sl;
      int h = s / 30, w = s - h * 30;
      int p = (h + 1) * 32 + (w + 1);
      *(uint4*)&qt[((size_t)(b * 1024 + p)) * 128 + c16 * 8] =
          *(uint4*)&t[sl * 128 + c16 * 8];
    }
  }
}

// ---------------- sse: fp32 SSE, 8 float4/thread, wave-shuffle reduce -------
__global__ __launch_bounds__(256) void sse_k(const float4* __restrict__ z4,
    const float* __restrict__ cb, const int* __restrict__ idxArr,
    float* __restrict__ sse) {
  int base = blockIdx.x * 2048 + threadIdx.x;             // 900 blocks exact
  float se = 0.f;
  #pragma unroll
  for (int it = 0; it < 8; ++it) {
    int i = base + it * 256;
    int f = i * 4;
    int n = f >> 7, d = f & 127;
    int k = idxArr[n];
    float4 zv = z4[i];
    float4 cv = *(const float4*)&cb[k * 128 + d];
    float dx = cv.x - zv.x, dy = cv.y - zv.y;
    float dz = cv.z - zv.z, dw = cv.w - zv.w;
    se += dx * dx + dy * dy + dz * dz + dw * dw;
  }
  #pragma unroll
  for (int o = 32; o > 0; o >>= 1) se += __shfl_down(se, o, 64);
  __shared__ float red[4];
  if ((threadIdx.x & 63) == 0) red[threadIdx.x >> 6] = se;
  __syncthreads();
  if (threadIdx.x == 0)
    atomicAdd(sse, red[0] + red[1] + red[2] + red[3]);
}

// ---------------- convT1 (MFMA, B in LDS): qt -> relu -> yt bf16 ------------
__global__ __launch_bounds__(256, 2) void convt1m_k(const bf16_t* __restrict__ qt,
    const bf16_t* __restrict__ wd1, const float* __restrict__ bias,
    ushort* __restrict__ yt) {
  __shared__ __align__(16) bf16_t as_[98 * 136];
  __shared__ __align__(16) bf16_t bs_[128 * 136];
  int blk = blockIdx.x;                                   // 64*16
  int b = blk >> 4, rt = blk & 15;
  int tid = threadIdx.x, wv = tid >> 6, ln = tid & 63;
  const float4* src = (const float4*)(qt + (size_t)b * 1024 * 128);
  #pragma unroll
  for (int s = 0; s < 7; ++s) {
    int f = s * 256 + tid;                                // 1568 f4s
    if (f < 1568) {
      int lp = f >> 4, c16 = f & 15;
      int gr = rt * 64 + lp;
      if (gr > 1023) gr = 1023;                           // rt=15 guard
      *(float4*)&as_[lp * 136 + c16 * 8] = src[gr * 16 + c16];
    }
  }
  int m = wv * 16 + (ln & 15), q = ln >> 4;
  f32x4 acc8[8];
  #pragma unroll
  for (int c = 0; c < 8; ++c) acc8[c] = (f32x4){0.f, 0.f, 0.f, 0.f};
  const float4* w4 = (const float4*)wd1;
  #pragma unroll
  for (int t = 0; t < 4; ++t) {
    __syncthreads();
    #pragma unroll
    for (int s = 0; s < 8; ++s) {
      int f = s * 256 + tid;
      int co = f >> 4, c16 = f & 15;
      *(float4*)&bs_[co * 136 + c16 * 8] = w4[t * 2048 + f];
    }
    __syncthreads();
    int off = (t >> 1) * 32 + (t & 1);
    bf16x8 af[4];
    #pragma unroll
    for (int kk = 0; kk < 4; ++kk)
      af[kk] = *(const bf16x8*)&as_[(m + off) * 136 + kk * 32 + q * 8];
    #pragma unroll
    for (int cot = 0; cot < 8; ++cot) {
      #pragma unroll
      for (int kk = 0; kk < 4; ++kk) {
        bf16x8 bf = *(const bf16x8*)&bs_[(cot * 16 + (ln & 15)) * 136 +
                                         kk * 32 + q * 8];
        acc8[cot] = __builtin_amdgcn_mfma_f32_16x16x32_bf16(af[kk], bf,
                                                            acc8[cot], 0, 0, 0);
      }
    }
  }
  #pragma unroll
  for (int cot = 0; cot < 8; ++cot) {
    int co = cot * 16 + (ln & 15);
    float bv = bias[co];
    #pragma unroll
    for (int r = 0; r < 4; ++r) {
      int mo = wv * 16 + q * 4 + r;
      int orow = rt * 2 + (mo >> 5), ocol = mo & 31;
      if (orow < 31 && ocol < 31) {
        float v = fmaxf(acc8[cot][r] + bv, 0.f);
        bf16_t h = (bf16_t)v;
        yt[((size_t)b * 1156 + (orow + 1) * 34 + (ocol + 1)) * 128 + co] =
            *(ushort*)&h;
      }
    }
  }
}

// ---------------- convT2 (MFMA): yt -> out fp32 ------------------------------
__global__ __launch_bounds__(256, 2) void convt2m_k(const bf16_t* __restrict__ yt,
    const bf16_t* __restrict__ wt2, const float* __restrict__ bias,
    float* __restrict__ out) {
  __shared__ __align__(16) bf16_t as_[128 * 136];         // 34.8 KB
  int b = blockIdx.x >> 4, rt = blockIdx.x & 15;          // grid = 64*16
  int tid = threadIdx.x, wv = tid >> 6, ln = tid & 63;
  const float4* src = (const float4*)(yt + ((size_t)b * 1156 + rt * 68) * 128);
  #pragma unroll
  for (int s = 0; s < 8; ++s) {
    int f = s * 256 + tid;
    int lp = f >> 4, c16 = f & 15;
    *(float4*)&as_[lp * 136 + c16 * 8] = src[f];
  }
  __syncthreads();
  int mloc = wv * 16 + (ln & 15), q = ln >> 4;
  int qh = mloc >> 5, qw = mloc & 31;                     // local quadrant pos
  int base = (qh + 1) * 34 + qw + 1;                      // in staged window
  f32x4 acc = {0.f, 0.f, 0.f, 0.f};
  #pragma unroll
  for (int kc = 0; kc < 16; ++kc) {
    int tap = kc >> 2;
    int toff = (tap & 1) + (tap >> 1) * 34;               // 0,1,34,35
    bf16x8 af = *(const bf16x8*)&as_[(base - toff) * 136 +
                                     (kc & 3) * 32 + q * 8];
    bf16x8 bf = *(const bf16x8*)&wt2[(size_t)(ln & 15) * 512 + kc * 32 + q * 8];
    acc = __builtin_amdgcn_mfma_f32_16x16x32_bf16(af, bf, acc, 0, 0, 0);
  }
  __syncthreads();                                        // as_ reads done
  float* bb = (float*)as_;                                // bounce: 64x16 f32
  #pragma unroll
  for (int r = 0; r < 4; ++r)
    bb[(wv * 16 + q * 4 + r) * 16 + (ln & 15)] = acc[r];
  __syncthreads();
  if (tid < 192) {
    int row_id = tid >> 4;                                // co*4 + ohoff
    int co = row_id >> 2, ohoff = row_id & 3;
    int qhl = ohoff >> 1, ph = ohoff & 1;
    float bv = bias[co];
    int ow0 = (tid & 15) * 4;
    float tmp[4];
    #pragma unroll
    for (int e = 0; e < 4; ++e) {
      int ow = ow0 + e;
      tmp[e] = bb[(qhl * 32 + (ow >> 1)) * 16 + co * 4 + ph * 2 + (ow & 1)]
               + bv;
    }
    *(float4*)&out[((size_t)(b * 3 + co)) * 4096 + (rt * 4 + ohoff) * 64 + ow0]
        = *(float4*)tmp;
  }
}

// ---------------- finalize: loss + perplexity -------------------------------
__global__ __launch_bounds__(256) void fin_k(const unsigned* __restrict__ hist,
    const float* __restrict__ sse, float* __restrict__ out) {
  __shared__ float red[256];
  float e = 0.f;
  for (int k = threadIdx.x; k < K_; k += 256) {
    float p = (float)hist[k] * (1.0f / (float)NROWS_);
    e += p * logf(p + 1e-10f);
  }
  red[threadIdx.x] = e;
  __syncthreads();
  #pragma unroll
  for (int t = 128; t > 0; t >>= 1) {
    if (threadIdx.x < t) red[threadIdx.x] += red[threadIdx.x + t];
    __syncthreads();
  }
  if (threadIdx.x == 0) {
    out[786432] = 1.25f * (*sse) * (1.0f / (float)NELEM_);
    out[786433] = expf(-red[0]);
  }
}

extern "C" void kernel_launch(void* const* d_in, const int* in_sizes, int n_in,
                              void* d_out, int out_size, void* d_ws,
                              size_t ws_size, hipStream_t stream) {
  (void)in_sizes; (void)n_in; (void)out_size; (void)ws_size;
  const float* x   = (const float*)d_in[0];
  const float* ew1 = (const float*)d_in[1];
  const float* eb1 = (const float*)d_in[2];
  const float* ew2 = (const float*)d_in[3];
  const float* eb2 = (const float*)d_in[4];
  const float* cb  = (const float*)d_in[5];
  const float* dw1 = (const float*)d_in[6];
  const float* db1 = (const float*)d_in[7];
  const float* dw2 = (const float*)d_in[8];
  const float* db2 = (const float*)d_in[9];
  float* out = (float*)d_out;
  char* ws = (char*)d_ws;

  // ws layout (~97.5 MB, aliased by liveness):
  //  [0, 35,684,352)            yt bf16 18.94 MB (zeroed; convt1m->convt2m)
  //  [35,684,352, 65,175,552)   z fp32 (conv2m->sse)
  //  [65,175,552, 81,985,536)   z1t bf16 +slack (conv1m->conv2m) then qt bf16
  //  [81,985,536, 96,731,136)   zbuf bf16 (conv2m->vq1)
  //  [96,731,136 ..)  cbb | wc2 | wd1 | idxArr | hist | cnorm | sse | wt2 | wc1
  ushort*   yt    = (ushort*)(ws);
  float*    z     = (float*)(ws + 35684352);
  bf16_t*   z1t   = (bf16_t*)(ws + 65175552);
  bf16_t*   qt    = (bf16_t*)(ws + 65175552);
  ushort*   zbuf  = (ushort*)(ws + 81985536);
  bf16_t*   cbb   = (bf16_t*)(ws + 96731136);
  bf16_t*   wc2   = (bf16_t*)(ws + 96993280);
  bf16_t*   wd1   = (bf16_t*)(ws + 97124352);
  int*      idxArr= (int*)(ws + 97255424);
  unsigned* hist  = (unsigned*)(ws + 97485824);
  float*    cnorm = (float*)(ws + 97489920);
  float*    sse   = (float*)(ws + 97494016);
  bf16_t*   wt2   = (bf16_t*)(ws + 97497088);
  bf16_t*   wc1   = (bf16_t*)(ws + 97513472);

  wprep_k<<<dim3(256), dim3(256), 0, stream>>>(ew1, ew2, dw1, dw2, cb,
                                               wc1, wc2, wd1, wt2,
                                               cbb, cnorm, hist, sse);
  conv1m_k<<<dim3(1024), dim3(256), 0, stream>>>(x, wc1, eb1, (ushort*)z1t);
  conv2m_k<<<dim3(960), dim3(256), 0, stream>>>(z1t, wc2, eb2, z, zbuf);
  vq1_k<<<dim3(900), dim3(256), 0, stream>>>((const bf16_t*)zbuf, cbb, cnorm,
                                             idxArr, hist);
  zero_k<<<dim3(4624), dim3(256), 0, stream>>>((float4*)yt, 1183744);
  zero_k<<<dim3(4104), dim3(256), 0, stream>>>((float4*)qt, 1050624);
  tq_k<<<dim3(960), dim3(256), 0, stream>>>(cbb, idxArr, (ushort*)qt);
  sse_k<<<dim3(900), dim3(256), 0, stream>>>((const float4*)z, cb, idxArr,
                                             sse);
  convt1m_k<<<dim3(1024), dim3(256), 0, stream>>>(qt, wd1, db1, yt);
  convt2m_k<<<dim3(1024), dim3(256), 0, stream>>>((const bf16_t*)yt, wt2, db2,
                                                  out);
  fin_k<<<dim3(1), dim3(256), 0, stream>>>(hist, sse, out);
}

// Round 18
// 254.557 us; speedup vs baseline: 1.3392x; 1.0638x over previous
//
#include <hip/hip_runtime.h>

#define B_    64
#define CIN_  3
#define HW_   64
#define HID_  128
#define K_    1024
#define H1_   31      // after conv1 (stride2 k4)
#define H2_   30      // after conv2 (stride1 k2)
#define NROWS_ 57600  // B_*H2_*H2_
#define NELEM_ 7372800

typedef __bf16 bf16_t;
typedef __attribute__((ext_vector_type(8))) __bf16 bf16x8;
typedef __attribute__((ext_vector_type(4))) float f32x4;

// ---------------- wprep: all weight transposes + codebook prep --------------
__global__ __launch_bounds__(256) void wprep_k(const float* __restrict__ ew1,
    const float* __restrict__ ew2, const float* __restrict__ dw1,
    const float* __restrict__ dw2, const float* __restrict__ cb,
    bf16_t* __restrict__ wc1, bf16_t* __restrict__ wc2,
    bf16_t* __restrict__ wd1, bf16_t* __restrict__ wt2,
    bf16_t* __restrict__ cbb, float* __restrict__ cnorm,
    unsigned* __restrict__ hist, float* __restrict__ sse) {
  int id = blockIdx.x * 256 + threadIdx.x;                // grid 256 -> 65536
  int t = id >> 14, co = (id >> 7) & 127, ci = id & 127;
  wc2[id] = (bf16_t)ew2[(co * 128 + ci) * 4 + t];
  wd1[id] = (bf16_t)dw1[(ci * 128 + co) * 4 + (3 - t)];
  if (id < 8192) {
    int n = id >> 9, k = id & 511;
    int tap = k >> 7, c = k & 127;
    if (n < 12) {
      int nco = n >> 2, ph = (n >> 1) & 1, pw = n & 1;
      int off = (tap >> 1) * 8 + (tap & 1) * 2;           // 0,2,8,10
      wt2[id] = (bf16_t)dw2[c * 48 + nco * 16 + ph * 4 + pw + off];
    } else {
      wt2[id] = (bf16_t)0.f;
    }
    int c1 = id >> 6, k1 = id & 63;                       // wc1
    wc1[id] = (bf16_t)(k1 < 48 ? ew1[c1 * 48 + k1] : 0.f);
  }
  if (id < K_) {
    float s0 = 0.f;
    for (int d = 0; d < HID_; d += 4) {
      float4 v = *(const float4*)&cb[id * HID_ + d];
      bf16_t tt[4] = {(bf16_t)v.x, (bf16_t)v.y, (bf16_t)v.z, (bf16_t)v.w};
      *(ushort4*)&((ushort*)cbb)[id * HID_ + d] = *(ushort4*)tt;
      float f0 = (float)tt[0], f1 = (float)tt[1];
      float f2 = (float)tt[2], f3 = (float)tt[3];
      s0 += f0 * f0 + f1 * f1 + f2 * f2 + f3 * f3;
    }
    cnorm[id] = s0;
    hist[id] = 0u;
  }
  if (id == 0) *sse = 0.f;
}

// ---------------- conv1 (MFMA, fused transpose): x -> relu -> z1t bf16 ------
__global__ __launch_bounds__(256, 2) void conv1m_k(const float* __restrict__ x,
    const bf16_t* __restrict__ wc1, const float* __restrict__ bias,
    ushort* __restrict__ z1t) {
  __shared__ __align__(16) bf16_t as_[64 * 72];           // 9 KB
  __shared__ __align__(16) bf16_t bs_[128 * 72];          // 18 KB
  int b = blockIdx.x >> 4, rt = blockIdx.x & 15;          // grid = 64*16
  int tid = threadIdx.x, wv = tid >> 6, ln = tid & 63;
  const float* xb = x + (size_t)b * 12288;
  #pragma unroll
  for (int it = 0; it < 16; ++it) {
    int e = it * 256 + tid;                               // 4096 A entries
    int p = e >> 6, k = e & 63;
    float v = 0.f;
    if (k < 48) {
      int ci = k >> 4, kh = (k >> 2) & 3, kw = k & 3;
      int row = 2 * rt + (p >> 5); if (row > 30) row = 30; // clamp: discarded
      int col = p & 31;            if (col > 30) col = 30;
      v = xb[ci * 4096 + (2 * row + kh) * 64 + 2 * col + kw];
    }
    as_[p * 72 + k] = (bf16_t)v;
  }
  {
    const float4* wg = (const float4*)wc1;
    #pragma unroll
    for (int it = 0; it < 4; ++it) {
      int fi = it * 256 + tid;                            // 1024 f4s
      int co = fi >> 3, k8 = fi & 7;
      *(float4*)&bs_[co * 72 + k8 * 8] = wg[fi];
    }
  }
  __syncthreads();
  int q = ln >> 4, l = ln & 15;
  f32x4 acc8[8];
  #pragma unroll
  for (int c = 0; c < 8; ++c) acc8[c] = (f32x4){0.f, 0.f, 0.f, 0.f};
  bf16x8 af[2];
  #pragma unroll
  for (int kk = 0; kk < 2; ++kk)
    af[kk] = *(const bf16x8*)&as_[(wv * 16 + l) * 72 + kk * 32 + q * 8];
  #pragma unroll
  for (int cot = 0; cot < 8; ++cot) {
    #pragma unroll
    for (int kk = 0; kk < 2; ++kk) {
      bf16x8 bf = *(const bf16x8*)&bs_[(cot * 16 + l) * 72 + kk * 32 + q * 8];
      acc8[cot] = __builtin_amdgcn_mfma_f32_16x16x32_bf16(af[kk], bf,
                                                          acc8[cot], 0, 0, 0);
    }
  }
  #pragma unroll
  for (int cot = 0; cot < 8; ++cot) {
    int co = cot * 16 + l;
    float bv = bias[co];
    #pragma unroll
    for (int r = 0; r < 4; ++r) {
      int pos = wv * 16 + q * 4 + r;
      int prow = 2 * rt + (pos >> 5), pcol = pos & 31;
      if (prow < 31 && pcol < 31) {
        float v = fmaxf(acc8[cot][r] + bv, 0.f);
        bf16_t h = (bf16_t)v;
        z1t[((size_t)(b * 1024 + prow * 32 + pcol)) * 128 + co] = *(ushort*)&h;
      }
    }
  }
}

// ---------------- conv2 (MFMA, B in LDS): z1t -> relu -> z + zbuf -----------
__global__ __launch_bounds__(256, 2) void conv2m_k(const bf16_t* __restrict__ z1t,
    const bf16_t* __restrict__ wc2, const float* __restrict__ bias,
    float* __restrict__ z, ushort* __restrict__ zbuf) {
  __shared__ __align__(16) bf16_t as_[98 * 136];          // rows m+off, off<=33
  __shared__ __align__(16) bf16_t bs_[128 * 136];
  int blk = blockIdx.x;                                   // 64*15
  int b = blk / 15, rt = blk % 15;
  int tid = threadIdx.x, wv = tid >> 6, ln = tid & 63;
  const float4* src = (const float4*)(z1t + ((size_t)b * 1024 + rt * 64) * 128);
  #pragma unroll
  for (int s = 0; s < 7; ++s) {
    int f = s * 256 + tid;                                // 98*16 = 1568 f4s
    if (f < 1568) {
      int lp = f >> 4, c16 = f & 15;                      // max row 993 < 1024
      *(float4*)&as_[lp * 136 + c16 * 8] = src[f];
    }
  }
  int m = wv * 16 + (ln & 15), q = ln >> 4;
  f32x4 acc8[8];
  #pragma unroll
  for (int c = 0; c < 8; ++c) acc8[c] = (f32x4){0.f, 0.f, 0.f, 0.f};
  const float4* w4 = (const float4*)wc2;
  #pragma unroll
  for (int t = 0; t < 4; ++t) {
    __syncthreads();                                      // bs_ reuse (+A 1st)
    #pragma unroll
    for (int s = 0; s < 8; ++s) {
      int f = s * 256 + tid;                              // 2048 f4s
      int co = f >> 4, c16 = f & 15;
      *(float4*)&bs_[co * 136 + c16 * 8] = w4[t * 2048 + f];
    }
    __syncthreads();
    int off = (t >> 1) * 32 + (t & 1);                    // tap offset in pos
    bf16x8 af[4];
    #pragma unroll
    for (int kk = 0; kk < 4; ++kk)
      af[kk] = *(const bf16x8*)&as_[(m + off) * 136 + kk * 32 + q * 8];
    #pragma unroll
    for (int cot = 0; cot < 8; ++cot) {
      #pragma unroll
      for (int kk = 0; kk < 4; ++kk) {
        bf16x8 bf = *(const bf16x8*)&bs_[(cot * 16 + (ln & 15)) * 136 +
                                         kk * 32 + q * 8];
        acc8[cot] = __builtin_amdgcn_mfma_f32_16x16x32_bf16(af[kk], bf,
                                                            acc8[cot], 0, 0, 0);
      }
    }
  }
  #pragma unroll
  for (int cot = 0; cot < 8; ++cot) {
    int co = cot * 16 + (ln & 15);
    float bv = bias[co];
    #pragma unroll
    for (int r = 0; r < 4; ++r) {
      int mo = wv * 16 + q * 4 + r;
      int ocol = mo & 31;
      if (ocol < 30) {
        int orow = rt * 2 + (mo >> 5);                    // always < 30
        float v = fmaxf(acc8[cot][r] + bv, 0.f);
        size_t idx = (size_t)(b * HID_ + co) * 900 + orow * 30 + ocol;
        z[idx] = v;
        bf16_t h = (bf16_t)v;
        zbuf[idx] = *(ushort*)&h;                         // fused cvt for vq1
      }
    }
  }
}

// ---------------- VQ phase 1 (MFMA): 64 rows x 1024 codes + hist ------------
// r13 structure + cnorm in LDS (r16/r17, measured ~61-63 us).
__global__ __launch_bounds__(256, 2) void vq1_k(const bf16_t* __restrict__ zb,
    const bf16_t* __restrict__ cbb, const float* __restrict__ cnorm,
    int* __restrict__ idxArr, unsigned* __restrict__ hist) {
  __shared__ __align__(16) bf16_t zs[64 * 136];           // 17 KB
  __shared__ __align__(16) bf16_t cbs[128 * 136];         // 34 KB
  __shared__ unsigned long long red[64 * 16];             // 8 KB
  __shared__ float cns[K_];                               // 4 KB
  int n0 = blockIdx.x * 64;                               // 900 blocks
  int tid = threadIdx.x;
  int wv = tid >> 6, ln = tid & 63;
  {
    const float4* zg4 = (const float4*)(zb + (size_t)n0 * HID_);
    #pragma unroll
    for (int s = 0; s < 4; ++s) {
      int f = s * 256 + tid;
      int row = f >> 4, seg = f & 15;
      *(float4*)&zs[row * 136 + seg * 8] = zg4[f];
    }
    ((float4*)cns)[tid] = ((const float4*)cnorm)[tid];    // 1024 floats once
  }
  __syncthreads();
  bf16x8 afr[4];
  #pragma unroll
  for (int kk = 0; kk < 4; ++kk)
    afr[kk] = *(const bf16x8*)&zs[(wv * 16 + (ln & 15)) * 136 + kk * 32 +
                                  (ln >> 4) * 8];
  unsigned long long best[4] = {~0ull, ~0ull, ~0ull, ~0ull};
  const float4* cg4 = (const float4*)cbb;
  for (int c0 = 0; c0 < K_; c0 += 128) {
    __syncthreads();
    #pragma unroll
    for (int s = 0; s < 8; ++s) {
      int f = s * 256 + tid;
      int code = f >> 4, seg = f & 15;
      *(float4*)&cbs[code * 136 + seg * 8] = cg4[(c0 + code) * 16 + seg];
    }
    __syncthreads();
    #pragma unroll 2
    for (int t = 0; t < 8; ++t) {
      f32x4 acc = {0.f, 0.f, 0.f, 0.f};
      #pragma unroll
      for (int kk = 0; kk < 4; ++kk) {
        bf16x8 bfr = *(const bf16x8*)&cbs[(t * 16 + (ln & 15)) * 136 +
                                          kk * 32 + (ln >> 4) * 8];
        acc = __builtin_amdgcn_mfma_f32_16x16x32_bf16(afr[kk], bfr, acc,
                                                      0, 0, 0);
      }
      int code = c0 + t * 16 + (ln & 15);
      float cn = cns[code];                               // LDS, ~broadcast
      #pragma unroll
      for (int r = 0; r < 4; ++r) {
        float dist = cn - 2.f * acc[r];
        unsigned u = __float_as_uint(dist);
        u = (u & 0x80000000u) ? ~u : (u | 0x80000000u);   // monotone map
        unsigned long long p = ((unsigned long long)u << 32) | (unsigned)code;
        if (p < best[r]) best[r] = p;                     // tie -> smaller k
      }
    }
  }
  __syncthreads();
  #pragma unroll
  for (int r = 0; r < 4; ++r)
    red[(wv * 16 + (ln >> 4) * 4 + r) * 16 + (ln & 15)] = best[r];
  __syncthreads();
  if (tid < 64) {
    unsigned long long b = ~0ull;
    #pragma unroll
    for (int c = 0; c < 16; ++c) {
      unsigned long long p = red[tid * 16 + c];
      if (p < b) b = p;
    }
    int bi = (int)(b & 0xffffffffu);
    idxArr[n0 + tid] = bi;
    atomicAdd(&hist[bi], 1u);                             // hist fused here
  }
}

// ---------------- tqsse: merged tq gather + sse + qt pad zero ---------------
// blocks [0,900): sse; [900,1860): tq; [1860,1876): zero qt's 124 pad pos/b.
__global__ __launch_bounds__(256) void tqsse_k(const float4* __restrict__ z4,
    const float* __restrict__ cb, const bf16_t* __restrict__ cbb,
    const int* __restrict__ idxArr, ushort* __restrict__ qt,
    float* __restrict__ sse) {
  __shared__ ushort t[60 * 128];                          // 15 KB (tq branch)
  __shared__ float red4[4];
  int bid = blockIdx.x, tid = threadIdx.x;
  if (bid < 900) {                                        // ---- sse ----
    int base = bid * 2048 + tid;
    float se = 0.f;
    #pragma unroll
    for (int it = 0; it < 8; ++it) {
      int i = base + it * 256;
      int f = i * 4;
      int n = f >> 7, d = f & 127;
      int k = idxArr[n];
      float4 zv = z4[i];
      float4 cv = *(const float4*)&cb[k * 128 + d];
      float dx = cv.x - zv.x, dy = cv.y - zv.y;
      float dz = cv.z - zv.z, dw = cv.w - zv.w;
      se += dx * dx + dy * dy + dz * dz + dw * dw;
    }
    #pragma unroll
    for (int o = 32; o > 0; o >>= 1) se += __shfl_down(se, o, 64);
    if ((tid & 63) == 0) red4[tid >> 6] = se;
    __syncthreads();
    if (tid == 0) atomicAdd(sse, red4[0] + red4[1] + red4[2] + red4[3]);
  } else if (bid < 1860) {                                // ---- tq ----
    int tb = bid - 900;
    int b = tb / 15, st = tb % 15;                        // 60-s tile
    int s0 = st * 60;
    #pragma unroll
    for (int it = 0; it < 8; ++it) {
      int task = it * 256 + tid;                          // sc*128 + c
      if (task < 1920) {
        int sc = task >> 7, c = task & 127;
        int f = b * 115200 + c * 900 + s0 + sc * 4;
        int n = f >> 7, d = f & 127;                      // d%4==0, no wrap
        int k = idxArr[n];
        ushort4 v = *(const ushort4*)((const ushort*)cbb + k * 128 + d);
        t[(sc * 4 + 0) * 128 + c] = v.x;
        t[(sc * 4 + 1) * 128 + c] = v.y;
        t[(sc * 4 + 2) * 128 + c] = v.z;
        t[(sc * 4 + 3) * 128 + c] = v.w;
      }
    }
    __syncthreads();
    #pragma unroll
    for (int it = 0; it < 4; ++it) {
      int task = it * 256 + tid;                          // sl*16 + c16
      if (task < 960) {
        int sl = task >> 4, c16 = task & 15;
        int s = s0 + sl;
        int h = s / 30, w = s - h * 30;
        int p = (h + 1) * 32 + (w + 1);
        *(uint4*)&qt[((size_t)(b * 1024 + p)) * 128 + c16 * 8] =
            *(uint4*)&t[sl * 128 + c16 * 8];
      }
    }
  } else {                                                // ---- qt pad ----
    int zb_ = (bid - 1860) * 4;                           // 4 b's per block
    uint4 zz = {0u, 0u, 0u, 0u};
    for (int e = tid; e < 4 * 124 * 16; e += 256) {
      int bb = zb_ + e / (124 * 16);
      int rem = e % (124 * 16);
      int pe = rem >> 4, s16 = rem & 15;
      int p;
      if (pe < 32) p = pe;                                // row 0
      else if (pe < 64) p = 31 * 32 + (pe - 32);          // row 31
      else {
        int idx = pe - 64;                                // rows 1..30, c 0/31
        p = (1 + (idx >> 1)) * 32 + ((idx & 1) ? 31 : 0);
      }
      *(uint4*)&qt[((size_t)(bb * 1024 + p)) * 128 + s16 * 8] = zz;
    }
  }
}

// ---------------- convT1 (MFMA, B in LDS): qt -> relu -> yt bf16 ------------
// yt pad zeroing fused (replaces zero_k): each block zeroes its own rows'
// pad cols {0,32,33}; rt=0 adds row 0, rt=15 adds rows 32,33. Disjoint.
__global__ __launch_bounds__(256, 2) void convt1m_k(const bf16_t* __restrict__ qt,
    const bf16_t* __restrict__ wd1, const float* __restrict__ bias,
    ushort* __restrict__ yt) {
  __shared__ __align__(16) bf16_t as_[98 * 136];
  __shared__ __align__(16) bf16_t bs_[128 * 136];
  int blk = blockIdx.x;                                   // 64*16
  int b = blk >> 4, rt = blk & 15;
  int tid = threadIdx.x, wv = tid >> 6, ln = tid & 63;
  {                                                       // fused pad zeroing
    uint4 zz = {0u, 0u, 0u, 0u};
    ushort* ytb = yt + (size_t)b * 1156 * 128;
    int nrows = (rt < 15) ? 2 : 1;                        // rt=15 owns row 31
    int r0 = 2 * rt + 1;
    for (int e = tid; e < nrows * 48; e += 256) {         // cols 0,32,33
      int rr = e / 48, rem = e % 48, cc = rem / 16, s16 = rem % 16;
      int col = (cc == 0) ? 0 : (cc == 1 ? 32 : 33);
      *(uint4*)&ytb[((size_t)((r0 + rr) * 34 + col)) * 128 + s16 * 8] = zz;
    }
    if (rt == 0)
      for (int e = tid; e < 34 * 16; e += 256)            // row 0
        *(uint4*)&ytb[((size_t)(e >> 4)) * 128 + (e & 15) * 8] = zz;
    if (rt == 15)
      for (int e = tid; e < 2 * 34 * 16; e += 256) {      // rows 32,33
        int rr = 32 + e / 544, rem = e % 544;
        *(uint4*)&ytb[((size_t)(rr * 34 + (rem >> 4))) * 128 + (rem & 15) * 8]
            = zz;
      }
  }
  const float4* src = (const float4*)(qt + (size_t)b * 1024 * 128);
  #pragma unroll
  for (int s = 0; s < 7; ++s) {
    int f = s * 256 + tid;                                // 1568 f4s
    if (f < 1568) {
      int lp = f >> 4, c16 = f & 15;
      int gr = rt * 64 + lp;
      if (gr > 1023) gr = 1023;                           // rt=15 guard
      *(float4*)&as_[lp * 136 + c16 * 8] = src[gr * 16 + c16];
    }
  }
  int m = wv * 16 + (ln & 15), q = ln >> 4;
  f32x4 acc8[8];
  #pragma unroll
  for (int c = 0; c < 8; ++c) acc8[c] = (f32x4){0.f, 0.f, 0.f, 0.f};
  const float4* w4 = (const float4*)wd1;
  #pragma unroll
  for (int t = 0; t < 4; ++t) {
    __syncthreads();
    #pragma unroll
    for (int s = 0; s < 8; ++s) {
      int f = s * 256 + tid;
      int co = f >> 4, c16 = f & 15;
      *(float4*)&bs_[co * 136 + c16 * 8] = w4[t * 2048 + f];
    }
    __syncthreads();
    int off = (t >> 1) * 32 + (t & 1);
    bf16x8 af[4];
    #pragma unroll
    for (int kk = 0; kk < 4; ++kk)
      af[kk] = *(const bf16x8*)&as_[(m + off) * 136 + kk * 32 + q * 8];
    #pragma unroll
    for (int cot = 0; cot < 8; ++cot) {
      #pragma unroll
      for (int kk = 0; kk < 4; ++kk) {
        bf16x8 bf = *(const bf16x8*)&bs_[(cot * 16 + (ln & 15)) * 136 +
                                         kk * 32 + q * 8];
        acc8[cot] = __builtin_amdgcn_mfma_f32_16x16x32_bf16(af[kk], bf,
                                                            acc8[cot], 0, 0, 0);
      }
    }
  }
  #pragma unroll
  for (int cot = 0; cot < 8; ++cot) {
    int co = cot * 16 + (ln & 15);
    float bv = bias[co];
    #pragma unroll
    for (int r = 0; r < 4; ++r) {
      int mo = wv * 16 + q * 4 + r;
      int orow = rt * 2 + (mo >> 5), ocol = mo & 31;
      if (orow < 31 && ocol < 31) {
        float v = fmaxf(acc8[cot][r] + bv, 0.f);
        bf16_t h = (bf16_t)v;
        yt[((size_t)b * 1156 + (orow + 1) * 34 + (ocol + 1)) * 128 + co] =
            *(ushort*)&h;
      }
    }
  }
}

// ---------------- convT2 (MFMA): yt -> out fp32, + fused finalize -----------
// Block 0 additionally computes loss+perplexity (hist/sse final by stream
// order: vq1 and tqsse complete before convt2m launches).
__global__ __launch_bounds__(256, 2) void convt2m_k(const bf16_t* __restrict__ yt,
    const bf16_t* __restrict__ wt2, const float* __restrict__ bias,
    const unsigned* __restrict__ hist, const float* __restrict__ sse,
    float* __restrict__ out) {
  __shared__ __align__(16) bf16_t as_[128 * 136];         // 34.8 KB
  __shared__ float redf[256];                             // 1 KB (fin branch)
  int b = blockIdx.x >> 4, rt = blockIdx.x & 15;          // grid = 64*16
  int tid = threadIdx.x, wv = tid >> 6, ln = tid & 63;
  const float4* src = (const float4*)(yt + ((size_t)b * 1156 + rt * 68) * 128);
  #pragma unroll
  for (int s = 0; s < 8; ++s) {
    int f = s * 256 + tid;
    int lp = f >> 4, c16 = f & 15;
    *(float4*)&as_[lp * 136 + c16 * 8] = src[f];
  }
  __syncthreads();
  int mloc = wv * 16 + (ln & 15), q = ln >> 4;
  int qh = mloc >> 5, qw = mloc & 31;                     // local quadrant pos
  int base = (qh + 1) * 34 + qw + 1;                      // in staged window
  f32x4 acc = {0.f, 0.f, 0.f, 0.f};
  #pragma unroll
  for (int kc = 0; kc < 16; ++kc) {
    int tap = kc >> 2;
    int toff = (tap & 1) + (tap >> 1) * 34;               // 0,1,34,35
    bf16x8 af = *(const bf16x8*)&as_[(base - toff) * 136 +
                                     (kc & 3) * 32 + q * 8];
    bf16x8 bf = *(const bf16x8*)&wt2[(size_t)(ln & 15) * 512 + kc * 32 + q * 8];
    acc = __builtin_amdgcn_mfma_f32_16x16x32_bf16(af, bf, acc, 0, 0, 0);
  }
  __syncthreads();                                        // as_ reads done
  float* bb = (float*)as_;                                // bounce: 64x16 f32
  #pragma unroll
  for (int r = 0; r < 4; ++r)
    bb[(wv * 16 + q * 4 + r) * 16 + (ln & 15)] = acc[r];
  __syncthreads();
  if (tid < 192) {
    int row_id = tid >> 4;                                // co*4 + ohoff
    int co = row_id >> 2, ohoff = row_id & 3;
    int qhl = ohoff >> 1, ph = ohoff & 1;
    float bv = bias[co];
    int ow0 = (tid & 15) * 4;
    float tmp[4];
    #pragma unroll
    for (int e = 0; e < 4; ++e) {
      int ow = ow0 + e;
      tmp[e] = bb[(qhl * 32 + (ow >> 1)) * 16 + co * 4 + ph * 2 + (ow & 1)]
               + bv;
    }
    *(float4*)&out[((size_t)(b * 3 + co)) * 4096 + (rt * 4 + ohoff) * 64 + ow0]
        = *(float4*)tmp;
  }
  if (blockIdx.x == 0) {                                  // ---- fused fin ----
    float e = 0.f;
    for (int k = tid; k < K_; k += 256) {
      float p = (float)hist[k] * (1.0f / (float)NROWS_);
      e += p * logf(p + 1e-10f);
    }
    redf[tid] = e;
    __syncthreads();
    #pragma unroll
    for (int t = 128; t > 0; t >>= 1) {
      if (tid < t) redf[tid] += redf[tid + t];
      __syncthreads();
    }
    if (tid == 0) {
      out[786432] = 1.25f * (*sse) * (1.0f / (float)NELEM_);
      out[786433] = expf(-redf[0]);
    }
  }
}

extern "C" void kernel_launch(void* const* d_in, const int* in_sizes, int n_in,
                              void* d_out, int out_size, void* d_ws,
                              size_t ws_size, hipStream_t stream) {
  (void)in_sizes; (void)n_in; (void)out_size; (void)ws_size;
  const float* x   = (const float*)d_in[0];
  const float* ew1 = (const float*)d_in[1];
  const float* eb1 = (const float*)d_in[2];
  const float* ew2 = (const float*)d_in[3];
  const float* eb2 = (const float*)d_in[4];
  const float* cb  = (const float*)d_in[5];
  const float* dw1 = (const float*)d_in[6];
  const float* db1 = (const float*)d_in[7];
  const float* dw2 = (const float*)d_in[8];
  const float* db2 = (const float*)d_in[9];
  float* out = (float*)d_out;
  char* ws = (char*)d_ws;

  // ws layout (~97.5 MB, aliased by liveness):
  //  [0, 35,684,352)            yt bf16 18.94 MB (pad zeroed in convt1m)
  //  [35,684,352, 65,175,552)   z fp32 (conv2m->tqsse)
  //  [65,175,552, 81,985,536)   z1t bf16 (conv1m->conv2m) then qt bf16
  //  [81,985,536, 96,731,136)   zbuf bf16 (conv2m->vq1)
  //  [96,731,136 ..)  cbb | wc2 | wd1 | idxArr | hist | cnorm | sse | wt2 | wc1
  ushort*   yt    = (ushort*)(ws);
  float*    z     = (float*)(ws + 35684352);
  bf16_t*   z1t   = (bf16_t*)(ws + 65175552);
  bf16_t*   qt    = (bf16_t*)(ws + 65175552);
  ushort*   zbuf  = (ushort*)(ws + 81985536);
  bf16_t*   cbb   = (bf16_t*)(ws + 96731136);
  bf16_t*   wc2   = (bf16_t*)(ws + 96993280);
  bf16_t*   wd1   = (bf16_t*)(ws + 97124352);
  int*      idxArr= (int*)(ws + 97255424);
  unsigned* hist  = (unsigned*)(ws + 97485824);
  float*    cnorm = (float*)(ws + 97489920);
  float*    sse   = (float*)(ws + 97494016);
  bf16_t*   wt2   = (bf16_t*)(ws + 97497088);
  bf16_t*   wc1   = (bf16_t*)(ws + 97513472);

  wprep_k<<<dim3(256), dim3(256), 0, stream>>>(ew1, ew2, dw1, dw2, cb,
                                               wc1, wc2, wd1, wt2,
                                               cbb, cnorm, hist, sse);
  conv1m_k<<<dim3(1024), dim3(256), 0, stream>>>(x, wc1, eb1, (ushort*)z1t);
  conv2m_k<<<dim3(960), dim3(256), 0, stream>>>(z1t, wc2, eb2, z, zbuf);
  vq1_k<<<dim3(900), dim3(256), 0, stream>>>((const bf16_t*)zbuf, cbb, cnorm,
                                             idxArr, hist);
  tqsse_k<<<dim3(1876), dim3(256), 0, stream>>>((const float4*)z, cb, cbb,
                                                idxArr, (ushort*)qt, sse);
  convt1m_k<<<dim3(1024), dim3(256), 0, stream>>>(qt, wd1, db1, yt);
  convt2m_k<<<dim3(1024), dim3(256), 0, stream>>>((const bf16_t*)yt, wt2, db2,
                                                  hist, sse, out);
}

// Round 19
// 231.165 us; speedup vs baseline: 1.4747x; 1.1012x over previous
//
#include <hip/hip_runtime.h>

#define B_    64
#define CIN_  3
#define HW_   64
#define HID_  128
#define K_    1024
#define H1_   31      // after conv1 (stride2 k4)
#define H2_   30      // after conv2 (stride1 k2)
#define NROWS_ 57600  // B_*H2_*H2_
#define NELEM_ 7372800

typedef __bf16 bf16_t;
typedef __attribute__((ext_vector_type(8))) __bf16 bf16x8;
typedef __attribute__((ext_vector_type(4))) float f32x4;

// ---------------- wprep: all weight transposes + codebook prep --------------
__global__ __launch_bounds__(256) void wprep_k(const float* __restrict__ ew1,
    const float* __restrict__ ew2, const float* __restrict__ dw1,
    const float* __restrict__ dw2, const float* __restrict__ cb,
    bf16_t* __restrict__ wc1, bf16_t* __restrict__ wc2,
    bf16_t* __restrict__ wd1, bf16_t* __restrict__ wt2,
    bf16_t* __restrict__ cbb, float* __restrict__ cnorm,
    unsigned* __restrict__ hist, float* __restrict__ sse) {
  int id = blockIdx.x * 256 + threadIdx.x;                // grid 256 -> 65536
  int t = id >> 14, co = (id >> 7) & 127, ci = id & 127;
  wc2[id] = (bf16_t)ew2[(co * 128 + ci) * 4 + t];
  wd1[id] = (bf16_t)dw1[(ci * 128 + co) * 4 + (3 - t)];
  if (id < 8192) {
    int n = id >> 9, k = id & 511;
    int tap = k >> 7, c = k & 127;
    if (n < 12) {
      int nco = n >> 2, ph = (n >> 1) & 1, pw = n & 1;
      int off = (tap >> 1) * 8 + (tap & 1) * 2;           // 0,2,8,10
      wt2[id] = (bf16_t)dw2[c * 48 + nco * 16 + ph * 4 + pw + off];
    } else {
      wt2[id] = (bf16_t)0.f;
    }
    int c1 = id >> 6, k1 = id & 63;                       // wc1
    wc1[id] = (bf16_t)(k1 < 48 ? ew1[c1 * 48 + k1] : 0.f);
  }
  if (id < K_) {
    float s0 = 0.f;
    for (int d = 0; d < HID_; d += 4) {
      float4 v = *(const float4*)&cb[id * HID_ + d];
      bf16_t tt[4] = {(bf16_t)v.x, (bf16_t)v.y, (bf16_t)v.z, (bf16_t)v.w};
      *(ushort4*)&((ushort*)cbb)[id * HID_ + d] = *(ushort4*)tt;
      float f0 = (float)tt[0], f1 = (float)tt[1];
      float f2 = (float)tt[2], f3 = (float)tt[3];
      s0 += f0 * f0 + f1 * f1 + f2 * f2 + f3 * f3;
    }
    cnorm[id] = s0;
    hist[id] = 0u;
  }
  if (id == 0) *sse = 0.f;
}

// ---------------- conv1 (MFMA, fused transpose): x -> relu -> z1t bf16 ------
__global__ __launch_bounds__(256, 2) void conv1m_k(const float* __restrict__ x,
    const bf16_t* __restrict__ wc1, const float* __restrict__ bias,
    ushort* __restrict__ z1t) {
  __shared__ __align__(16) bf16_t as_[64 * 72];           // 9 KB
  __shared__ __align__(16) bf16_t bs_[128 * 72];          // 18 KB
  int b = blockIdx.x >> 4, rt = blockIdx.x & 15;          // grid = 64*16
  int tid = threadIdx.x, wv = tid >> 6, ln = tid & 63;
  const float* xb = x + (size_t)b * 12288;
  #pragma unroll
  for (int it = 0; it < 16; ++it) {
    int e = it * 256 + tid;                               // 4096 A entries
    int p = e >> 6, k = e & 63;
    float v = 0.f;
    if (k < 48) {
      int ci = k >> 4, kh = (k >> 2) & 3, kw = k & 3;
      int row = 2 * rt + (p >> 5); if (row > 30) row = 30; // clamp: discarded
      int col = p & 31;            if (col > 30) col = 30;
      v = xb[ci * 4096 + (2 * row + kh) * 64 + 2 * col + kw];
    }
    as_[p * 72 + k] = (bf16_t)v;
  }
  {
    const float4* wg = (const float4*)wc1;
    #pragma unroll
    for (int it = 0; it < 4; ++it) {
      int fi = it * 256 + tid;                            // 1024 f4s
      int co = fi >> 3, k8 = fi & 7;
      *(float4*)&bs_[co * 72 + k8 * 8] = wg[fi];
    }
  }
  __syncthreads();
  int q = ln >> 4, l = ln & 15;
  f32x4 acc8[8];
  #pragma unroll
  for (int c = 0; c < 8; ++c) acc8[c] = (f32x4){0.f, 0.f, 0.f, 0.f};
  bf16x8 af[2];
  #pragma unroll
  for (int kk = 0; kk < 2; ++kk)
    af[kk] = *(const bf16x8*)&as_[(wv * 16 + l) * 72 + kk * 32 + q * 8];
  #pragma unroll
  for (int cot = 0; cot < 8; ++cot) {
    #pragma unroll
    for (int kk = 0; kk < 2; ++kk) {
      bf16x8 bf = *(const bf16x8*)&bs_[(cot * 16 + l) * 72 + kk * 32 + q * 8];
      acc8[cot] = __builtin_amdgcn_mfma_f32_16x16x32_bf16(af[kk], bf,
                                                          acc8[cot], 0, 0, 0);
    }
  }
  #pragma unroll
  for (int cot = 0; cot < 8; ++cot) {
    int co = cot * 16 + l;
    float bv = bias[co];
    #pragma unroll
    for (int r = 0; r < 4; ++r) {
      int pos = wv * 16 + q * 4 + r;
      int prow = 2 * rt + (pos >> 5), pcol = pos & 31;
      if (prow < 31 && pcol < 31) {
        float v = fmaxf(acc8[cot][r] + bv, 0.f);
        bf16_t h = (bf16_t)v;
        z1t[((size_t)(b * 1024 + prow * 32 + pcol)) * 128 + co] = *(ushort*)&h;
      }
    }
  }
}

// ---------------- conv2 (MFMA, B in LDS): z1t -> relu -> zbuf bf16 only -----
// fp32 z store removed (r19): SSE is now computed inside vq1 from the
// MFMA-expanded form, so the fp32 z tensor has no consumer.
__global__ __launch_bounds__(256, 2) void conv2m_k(const bf16_t* __restrict__ z1t,
    const bf16_t* __restrict__ wc2, const float* __restrict__ bias,
    ushort* __restrict__ zbuf) {
  __shared__ __align__(16) bf16_t as_[98 * 136];          // rows m+off, off<=33
  __shared__ __align__(16) bf16_t bs_[128 * 136];
  int blk = blockIdx.x;                                   // 64*15
  int b = blk / 15, rt = blk % 15;
  int tid = threadIdx.x, wv = tid >> 6, ln = tid & 63;
  const float4* src = (const float4*)(z1t + ((size_t)b * 1024 + rt * 64) * 128);
  #pragma unroll
  for (int s = 0; s < 7; ++s) {
    int f = s * 256 + tid;                                // 98*16 = 1568 f4s
    if (f < 1568) {
      int lp = f >> 4, c16 = f & 15;                      // max row 993 < 1024
      *(float4*)&as_[lp * 136 + c16 * 8] = src[f];
    }
  }
  int m = wv * 16 + (ln & 15), q = ln >> 4;
  f32x4 acc8[8];
  #pragma unroll
  for (int c = 0; c < 8; ++c) acc8[c] = (f32x4){0.f, 0.f, 0.f, 0.f};
  const float4* w4 = (const float4*)wc2;
  #pragma unroll
  for (int t = 0; t < 4; ++t) {
    __syncthreads();                                      // bs_ reuse (+A 1st)
    #pragma unroll
    for (int s = 0; s < 8; ++s) {
      int f = s * 256 + tid;                              // 2048 f4s
      int co = f >> 4, c16 = f & 15;
      *(float4*)&bs_[co * 136 + c16 * 8] = w4[t * 2048 + f];
    }
    __syncthreads();
    int off = (t >> 1) * 32 + (t & 1);                    // tap offset in pos
    bf16x8 af[4];
    #pragma unroll
    for (int kk = 0; kk < 4; ++kk)
      af[kk] = *(const bf16x8*)&as_[(m + off) * 136 + kk * 32 + q * 8];
    #pragma unroll
    for (int cot = 0; cot < 8; ++cot) {
      #pragma unroll
      for (int kk = 0; kk < 4; ++kk) {
        bf16x8 bf = *(const bf16x8*)&bs_[(cot * 16 + (ln & 15)) * 136 +
                                         kk * 32 + q * 8];
        acc8[cot] = __builtin_amdgcn_mfma_f32_16x16x32_bf16(af[kk], bf,
                                                            acc8[cot], 0, 0, 0);
      }
    }
  }
  #pragma unroll
  for (int cot = 0; cot < 8; ++cot) {
    int co = cot * 16 + (ln & 15);
    float bv = bias[co];
    #pragma unroll
    for (int r = 0; r < 4; ++r) {
      int mo = wv * 16 + q * 4 + r;
      int ocol = mo & 31;
      if (ocol < 30) {
        int orow = rt * 2 + (mo >> 5);                    // always < 30
        float v = fmaxf(acc8[cot][r] + bv, 0.f);
        bf16_t h = (bf16_t)v;
        zbuf[(size_t)(b * HID_ + co) * 900 + orow * 30 + ocol] = *(ushort*)&h;
      }
    }
  }
}

// ---------------- VQ phase 1 (MFMA): argmin + hist + FUSED SSE --------------
// r13 structure + cnorm in LDS (r16/r17). r19: SSE fused — for the winning
// code, dmin = |cb'-z'|^2 - |z'|^2 is the unmapped best; sse_row = |z'|^2 +
// dmin (bf16-consistent SSE; replaces the fp32-z sse pass entirely).
__global__ __launch_bounds__(256, 2) void vq1_k(const bf16_t* __restrict__ zb,
    const bf16_t* __restrict__ cbb, const float* __restrict__ cnorm,
    int* __restrict__ idxArr, unsigned* __restrict__ hist,
    float* __restrict__ sse) {
  __shared__ __align__(16) bf16_t zs[64 * 136];           // 17 KB
  __shared__ __align__(16) bf16_t cbs[128 * 136];         // 34 KB
  __shared__ unsigned long long red[64 * 16];             // 8 KB
  __shared__ float cns[K_];                               // 4 KB
  int n0 = blockIdx.x * 64;                               // 900 blocks
  int tid = threadIdx.x;
  int wv = tid >> 6, ln = tid & 63;
  {
    const float4* zg4 = (const float4*)(zb + (size_t)n0 * HID_);
    #pragma unroll
    for (int s = 0; s < 4; ++s) {
      int f = s * 256 + tid;
      int row = f >> 4, seg = f & 15;
      *(float4*)&zs[row * 136 + seg * 8] = zg4[f];
    }
    ((float4*)cns)[tid] = ((const float4*)cnorm)[tid];    // 1024 floats once
  }
  __syncthreads();
  bf16x8 afr[4];
  #pragma unroll
  for (int kk = 0; kk < 4; ++kk)
    afr[kk] = *(const bf16x8*)&zs[(wv * 16 + (ln & 15)) * 136 + kk * 32 +
                                  (ln >> 4) * 8];
  unsigned long long best[4] = {~0ull, ~0ull, ~0ull, ~0ull};
  const float4* cg4 = (const float4*)cbb;
  for (int c0 = 0; c0 < K_; c0 += 128) {
    __syncthreads();
    #pragma unroll
    for (int s = 0; s < 8; ++s) {
      int f = s * 256 + tid;
      int code = f >> 4, seg = f & 15;
      *(float4*)&cbs[code * 136 + seg * 8] = cg4[(c0 + code) * 16 + seg];
    }
    __syncthreads();
    #pragma unroll 2
    for (int t = 0; t < 8; ++t) {
      f32x4 acc = {0.f, 0.f, 0.f, 0.f};
      #pragma unroll
      for (int kk = 0; kk < 4; ++kk) {
        bf16x8 bfr = *(const bf16x8*)&cbs[(t * 16 + (ln & 15)) * 136 +
                                          kk * 32 + (ln >> 4) * 8];
        acc = __builtin_amdgcn_mfma_f32_16x16x32_bf16(afr[kk], bfr, acc,
                                                      0, 0, 0);
      }
      int code = c0 + t * 16 + (ln & 15);
      float cn = cns[code];                               // LDS, ~broadcast
      #pragma unroll
      for (int r = 0; r < 4; ++r) {
        float dist = cn - 2.f * acc[r];
        unsigned u = __float_as_uint(dist);
        u = (u & 0x80000000u) ? ~u : (u | 0x80000000u);   // monotone map
        unsigned long long p = ((unsigned long long)u << 32) | (unsigned)code;
        if (p < best[r]) best[r] = p;                     // tie -> smaller k
      }
    }
  }
  __syncthreads();
  #pragma unroll
  for (int r = 0; r < 4; ++r)
    red[(wv * 16 + (ln >> 4) * 4 + r) * 16 + (ln & 15)] = best[r];
  __syncthreads();
  if (tid < 64) {
    unsigned long long b = ~0ull;
    #pragma unroll
    for (int c = 0; c < 16; ++c) {
      unsigned long long p = red[tid * 16 + c];
      if (p < b) b = p;
    }
    int bi = (int)(b & 0xffffffffu);
    idxArr[n0 + tid] = bi;
    atomicAdd(&hist[bi], 1u);                             // hist fused
    // ---- fused SSE: unmap dmin, add |z'|^2 (row tid still in zs) ----
    unsigned hi = (unsigned)(b >> 32);
    unsigned orig = (hi & 0x80000000u) ? (hi & 0x7fffffffu) : ~hi;
    float dmin = __uint_as_float(orig);
    float zn = 0.f;
    #pragma unroll
    for (int s = 0; s < 16; ++s) {
      bf16x8 v = *(const bf16x8*)&zs[tid * 136 + s * 8];
      #pragma unroll
      for (int e = 0; e < 8; ++e) {
        float fv = (float)v[e];
        zn = fmaf(fv, fv, zn);
      }
    }
    float se = zn + dmin;
    #pragma unroll
    for (int o = 32; o > 0; o >>= 1) se += __shfl_down(se, o, 64);
    if (tid == 0) atomicAdd(sse, se);
  }
}

// ---------------- tqz: tq gather + qt pad zero (sse branch removed) ---------
// blocks [0,960): tq; [960,976): zero qt's 124 pad positions per b.
__global__ __launch_bounds__(256) void tqz_k(const bf16_t* __restrict__ cbb,
    const int* __restrict__ idxArr, ushort* __restrict__ qt) {
  __shared__ ushort t[60 * 128];                          // 15 KB
  int bid = blockIdx.x, tid = threadIdx.x;
  if (bid < 960) {                                        // ---- tq ----
    int b = bid / 15, st = bid % 15;                      // 60-s tile
    int s0 = st * 60;
    #pragma unroll
    for (int it = 0; it < 8; ++it) {
      int task = it * 256 + tid;                          // sc*128 + c
      if (task < 1920) {
        int sc = task >> 7, c = task & 127;
        int f = b * 115200 + c * 900 + s0 + sc * 4;
        int n = f >> 7, d = f & 127;                      // d%4==0, no wrap
        int k = idxArr[n];
        ushort4 v = *(const ushort4*)((const ushort*)cbb + k * 128 + d);
        t[(sc * 4 + 0) * 128 + c] = v.x;
        t[(sc * 4 + 1) * 128 + c] = v.y;
        t[(sc * 4 + 2) * 128 + c] = v.z;
        t[(sc * 4 + 3) * 128 + c] = v.w;
      }
    }
    __syncthreads();
    #pragma unroll
    for (int it = 0; it < 4; ++it) {
      int task = it * 256 + tid;                          // sl*16 + c16
      if (task < 960) {
        int sl = task >> 4, c16 = task & 15;
        int s = s0 + sl;
        int h = s / 30, w = s - h * 30;
        int p = (h + 1) * 32 + (w + 1);
        *(uint4*)&qt[((size_t)(b * 1024 + p)) * 128 + c16 * 8] =
            *(uint4*)&t[sl * 128 + c16 * 8];
      }
    }
  } else {                                                // ---- qt pad ----
    int zb_ = (bid - 960) * 4;                            // 4 b's per block
    uint4 zz = {0u, 0u, 0u, 0u};
    for (int e = tid; e < 4 * 124 * 16; e += 256) {
      int bb = zb_ + e / (124 * 16);
      int rem = e % (124 * 16);
      int pe = rem >> 4, s16 = rem & 15;
      int p;
      if (pe < 32) p = pe;                                // row 0
      else if (pe < 64) p = 31 * 32 + (pe - 32);          // row 31
      else {
        int idx = pe - 64;                                // rows 1..30, c 0/31
        p = (1 + (idx >> 1)) * 32 + ((idx & 1) ? 31 : 0);
      }
      *(uint4*)&qt[((size_t)(bb * 1024 + p)) * 128 + s16 * 8] = zz;
    }
  }
}

// ---------------- convT1 (MFMA, B in LDS): qt -> relu -> yt bf16 ------------
__global__ __launch_bounds__(256, 2) void convt1m_k(const bf16_t* __restrict__ qt,
    const bf16_t* __restrict__ wd1, const float* __restrict__ bias,
    ushort* __restrict__ yt) {
  __shared__ __align__(16) bf16_t as_[98 * 136];
  __shared__ __align__(16) bf16_t bs_[128 * 136];
  int blk = blockIdx.x;                                   // 64*16
  int b = blk >> 4, rt = blk & 15;
  int tid = threadIdx.x, wv = tid >> 6, ln = tid & 63;
  {                                                       // fused pad zeroing
    uint4 zz = {0u, 0u, 0u, 0u};
    ushort* ytb = yt + (size_t)b * 1156 * 128;
    int nrows = (rt < 15) ? 2 : 1;                        // rt=15 owns row 31
    int r0 = 2 * rt + 1;
    for (int e = tid; e < nrows * 48; e += 256) {         // cols 0,32,33
      int rr = e / 48, rem = e % 48, cc = rem / 16, s16 = rem % 16;
      int col = (cc == 0) ? 0 : (cc == 1 ? 32 : 33);
      *(uint4*)&ytb[((size_t)((r0 + rr) * 34 + col)) * 128 + s16 * 8] = zz;
    }
    if (rt == 0)
      for (int e = tid; e < 34 * 16; e += 256)            // row 0
        *(uint4*)&ytb[((size_t)(e >> 4)) * 128 + (e & 15) * 8] = zz;
    if (rt == 15)
      for (int e = tid; e < 2 * 34 * 16; e += 256) {      // rows 32,33
        int rr = 32 + e / 544, rem = e % 544;
        *(uint4*)&ytb[((size_t)(rr * 34 + (rem >> 4))) * 128 + (rem & 15) * 8]
            = zz;
      }
  }
  const float4* src = (const float4*)(qt + (size_t)b * 1024 * 128);
  #pragma unroll
  for (int s = 0; s < 7; ++s) {
    int f = s * 256 + tid;                                // 1568 f4s
    if (f < 1568) {
      int lp = f >> 4, c16 = f & 15;
      int gr = rt * 64 + lp;
      if (gr > 1023) gr = 1023;                           // rt=15 guard
      *(float4*)&as_[lp * 136 + c16 * 8] = src[gr * 16 + c16];
    }
  }
  int m = wv * 16 + (ln & 15), q = ln >> 4;
  f32x4 acc8[8];
  #pragma unroll
  for (int c = 0; c < 8; ++c) acc8[c] = (f32x4){0.f, 0.f, 0.f, 0.f};
  const float4* w4 = (const float4*)wd1;
  #pragma unroll
  for (int t = 0; t < 4; ++t) {
    __syncthreads();
    #pragma unroll
    for (int s = 0; s < 8; ++s) {
      int f = s * 256 + tid;
      int co = f >> 4, c16 = f & 15;
      *(float4*)&bs_[co * 136 + c16 * 8] = w4[t * 2048 + f];
    }
    __syncthreads();
    int off = (t >> 1) * 32 + (t & 1);
    bf16x8 af[4];
    #pragma unroll
    for (int kk = 0; kk < 4; ++kk)
      af[kk] = *(const bf16x8*)&as_[(m + off) * 136 + kk * 32 + q * 8];
    #pragma unroll
    for (int cot = 0; cot < 8; ++cot) {
      #pragma unroll
      for (int kk = 0; kk < 4; ++kk) {
        bf16x8 bf = *(const bf16x8*)&bs_[(cot * 16 + (ln & 15)) * 136 +
                                         kk * 32 + q * 8];
        acc8[cot] = __builtin_amdgcn_mfma_f32_16x16x32_bf16(af[kk], bf,
                                                            acc8[cot], 0, 0, 0);
      }
    }
  }
  #pragma unroll
  for (int cot = 0; cot < 8; ++cot) {
    int co = cot * 16 + (ln & 15);
    float bv = bias[co];
    #pragma unroll
    for (int r = 0; r < 4; ++r) {
      int mo = wv * 16 + q * 4 + r;
      int orow = rt * 2 + (mo >> 5), ocol = mo & 31;
      if (orow < 31 && ocol < 31) {
        float v = fmaxf(acc8[cot][r] + bv, 0.f);
        bf16_t h = (bf16_t)v;
        yt[((size_t)b * 1156 + (orow + 1) * 34 + (ocol + 1)) * 128 + co] =
            *(ushort*)&h;
      }
    }
  }
}

// ---------------- convT2 (MFMA): yt -> out fp32, + fused finalize -----------
__global__ __launch_bounds__(256, 2) void convt2m_k(const bf16_t* __restrict__ yt,
    const bf16_t* __restrict__ wt2, const float* __restrict__ bias,
    const unsigned* __restrict__ hist, const float* __restrict__ sse,
    float* __restrict__ out) {
  __shared__ __align__(16) bf16_t as_[128 * 136];         // 34.8 KB
  __shared__ float redf[256];                             // 1 KB (fin branch)
  int b = blockIdx.x >> 4, rt = blockIdx.x & 15;          // grid = 64*16
  int tid = threadIdx.x, wv = tid >> 6, ln = tid & 63;
  const float4* src = (const float4*)(yt + ((size_t)b * 1156 + rt * 68) * 128);
  #pragma unroll
  for (int s = 0; s < 8; ++s) {
    int f = s * 256 + tid;
    int lp = f >> 4, c16 = f & 15;
    *(float4*)&as_[lp * 136 + c16 * 8] = src[f];
  }
  __syncthreads();
  int mloc = wv * 16 + (ln & 15), q = ln >> 4;
  int qh = mloc >> 5, qw = mloc & 31;                     // local quadrant pos
  int base = (qh + 1) * 34 + qw + 1;                      // in staged window
  f32x4 acc = {0.f, 0.f, 0.f, 0.f};
  #pragma unroll
  for (int kc = 0; kc < 16; ++kc) {
    int tap = kc >> 2;
    int toff = (tap & 1) + (tap >> 1) * 34;               // 0,1,34,35
    bf16x8 af = *(const bf16x8*)&as_[(base - toff) * 136 +
                                     (kc & 3) * 32 + q * 8];
    bf16x8 bf = *(const bf16x8*)&wt2[(size_t)(ln & 15) * 512 + kc * 32 + q * 8];
    acc = __builtin_amdgcn_mfma_f32_16x16x32_bf16(af, bf, acc, 0, 0, 0);
  }
  __syncthreads();                                        // as_ reads done
  float* bb = (float*)as_;                                // bounce: 64x16 f32
  #pragma unroll
  for (int r = 0; r < 4; ++r)
    bb[(wv * 16 + q * 4 + r) * 16 + (ln & 15)] = acc[r];
  __syncthreads();
  if (tid < 192) {
    int row_id = tid >> 4;                                // co*4 + ohoff
    int co = row_id >> 2, ohoff = row_id & 3;
    int qhl = ohoff >> 1, ph = ohoff & 1;
    float bv = bias[co];
    int ow0 = (tid & 15) * 4;
    float tmp[4];
    #pragma unroll
    for (int e = 0; e < 4; ++e) {
      int ow = ow0 + e;
      tmp[e] = bb[(qhl * 32 + (ow >> 1)) * 16 + co * 4 + ph * 2 + (ow & 1)]
               + bv;
    }
    *(float4*)&out[((size_t)(b * 3 + co)) * 4096 + (rt * 4 + ohoff) * 64 + ow0]
        = *(float4*)tmp;
  }
  if (blockIdx.x == 0) {                                  // ---- fused fin ----
    float e = 0.f;
    for (int k = tid; k < K_; k += 256) {
      float p = (float)hist[k] * (1.0f / (float)NROWS_);
      e += p * logf(p + 1e-10f);
    }
    redf[tid] = e;
    __syncthreads();
    #pragma unroll
    for (int t = 128; t > 0; t >>= 1) {
      if (tid < t) redf[tid] += redf[tid + t];
      __syncthreads();
    }
    if (tid == 0) {
      out[786432] = 1.25f * (*sse) * (1.0f / (float)NELEM_);
      out[786433] = expf(-redf[0]);
    }
  }
}

extern "C" void kernel_launch(void* const* d_in, const int* in_sizes, int n_in,
                              void* d_out, int out_size, void* d_ws,
                              size_t ws_size, hipStream_t stream) {
  (void)in_sizes; (void)n_in; (void)out_size; (void)ws_size;
  const float* x   = (const float*)d_in[0];
  const float* ew1 = (const float*)d_in[1];
  const float* eb1 = (const float*)d_in[2];
  const float* ew2 = (const float*)d_in[3];
  const float* eb2 = (const float*)d_in[4];
  const float* cb  = (const float*)d_in[5];
  const float* dw1 = (const float*)d_in[6];
  const float* db1 = (const float*)d_in[7];
  const float* dw2 = (const float*)d_in[8];
  const float* db2 = (const float*)d_in[9];
  float* out = (float*)d_out;
  char* ws = (char*)d_ws;

  // ws layout (~97.5 MB, aliased by liveness; z fp32 region now unused):
  //  [0, 35,684,352)            yt bf16 18.94 MB (pad zeroed in convt1m)
  //  [65,175,552, 81,985,536)   z1t bf16 (conv1m->conv2m) then qt bf16
  //  [81,985,536, 96,731,136)   zbuf bf16 (conv2m->vq1)
  //  [96,731,136 ..)  cbb | wc2 | wd1 | idxArr | hist | cnorm | sse | wt2 | wc1
  ushort*   yt    = (ushort*)(ws);
  bf16_t*   z1t   = (bf16_t*)(ws + 65175552);
  bf16_t*   qt    = (bf16_t*)(ws + 65175552);
  ushort*   zbuf  = (ushort*)(ws + 81985536);
  bf16_t*   cbb   = (bf16_t*)(ws + 96731136);
  bf16_t*   wc2   = (bf16_t*)(ws + 96993280);
  bf16_t*   wd1   = (bf16_t*)(ws + 97124352);
  int*      idxArr= (int*)(ws + 97255424);
  unsigned* hist  = (unsigned*)(ws + 97485824);
  float*    cnorm = (float*)(ws + 97489920);
  float*    sse   = (float*)(ws + 97494016);
  bf16_t*   wt2   = (bf16_t*)(ws + 97497088);
  bf16_t*   wc1   = (bf16_t*)(ws + 97513472);

  wprep_k<<<dim3(256), dim3(256), 0, stream>>>(ew1, ew2, dw1, dw2, cb,
                                               wc1, wc2, wd1, wt2,
                                               cbb, cnorm, hist, sse);
  conv1m_k<<<dim3(1024), dim3(256), 0, stream>>>(x, wc1, eb1, (ushort*)z1t);
  conv2m_k<<<dim3(960), dim3(256), 0, stream>>>(z1t, wc2, eb2, zbuf);
  vq1_k<<<dim3(900), dim3(256), 0, stream>>>((const bf16_t*)zbuf, cbb, cnorm,
                                             idxArr, hist, sse);
  tqz_k<<<dim3(976), dim3(256), 0, stream>>>(cbb, idxArr, (ushort*)qt);
  convt1m_k<<<dim3(1024), dim3(256), 0, stream>>>(qt, wd1, db1, yt);
  convt2m_k<<<dim3(1024), dim3(256), 0, stream>>>((const bf16_t*)yt, wt2, db2,
                                                  hist, sse, out);
}

// Round 20
// 227.000 us; speedup vs baseline: 1.5017x; 1.0183x over previous
//
#include <hip/hip_runtime.h>

#define B_    64
#define CIN_  3
#define HW_   64
#define HID_  128
#define K_    1024
#define H1_   31      // after conv1 (stride2 k4)
#define H2_   30      // after conv2 (stride1 k2)
#define NROWS_ 57600  // B_*H2_*H2_
#define NELEM_ 7372800

typedef __bf16 bf16_t;
typedef __attribute__((ext_vector_type(8))) __bf16 bf16x8;
typedef __attribute__((ext_vector_type(4))) float f32x4;
typedef __attribute__((ext_vector_type(16))) float f32x16;

// ---------------- wprep: all weight transposes + codebook prep --------------
__global__ __launch_bounds__(256) void wprep_k(const float* __restrict__ ew1,
    const float* __restrict__ ew2, const float* __restrict__ dw1,
    const float* __restrict__ dw2, const float* __restrict__ cb,
    bf16_t* __restrict__ wc1, bf16_t* __restrict__ wc2,
    bf16_t* __restrict__ wd1, bf16_t* __restrict__ wt2,
    bf16_t* __restrict__ cbb, float* __restrict__ cnorm,
    unsigned* __restrict__ hist, float* __restrict__ sse) {
  int id = blockIdx.x * 256 + threadIdx.x;                // grid 256 -> 65536
  int t = id >> 14, co = (id >> 7) & 127, ci = id & 127;
  wc2[id] = (bf16_t)ew2[(co * 128 + ci) * 4 + t];
  wd1[id] = (bf16_t)dw1[(ci * 128 + co) * 4 + (3 - t)];
  if (id < 8192) {
    int n = id >> 9, k = id & 511;
    int tap = k >> 7, c = k & 127;
    if (n < 12) {
      int nco = n >> 2, ph = (n >> 1) & 1, pw = n & 1;
      int off = (tap >> 1) * 8 + (tap & 1) * 2;           // 0,2,8,10
      wt2[id] = (bf16_t)dw2[c * 48 + nco * 16 + ph * 4 + pw + off];
    } else {
      wt2[id] = (bf16_t)0.f;
    }
    int c1 = id >> 6, k1 = id & 63;                       // wc1
    wc1[id] = (bf16_t)(k1 < 48 ? ew1[c1 * 48 + k1] : 0.f);
  }
  if (id < K_) {
    float s0 = 0.f;
    for (int d = 0; d < HID_; d += 4) {
      float4 v = *(const float4*)&cb[id * HID_ + d];
      bf16_t tt[4] = {(bf16_t)v.x, (bf16_t)v.y, (bf16_t)v.z, (bf16_t)v.w};
      *(ushort4*)&((ushort*)cbb)[id * HID_ + d] = *(ushort4*)tt;
      float f0 = (float)tt[0], f1 = (float)tt[1];
      float f2 = (float)tt[2], f3 = (float)tt[3];
      s0 += f0 * f0 + f1 * f1 + f2 * f2 + f3 * f3;
    }
    cnorm[id] = s0;
    hist[id] = 0u;
  }
  if (id == 0) *sse = 0.f;
}

// ---------------- conv1 (MFMA, fused transpose): x -> relu -> z1t bf16 ------
__global__ __launch_bounds__(256, 2) void conv1m_k(const float* __restrict__ x,
    const bf16_t* __restrict__ wc1, const float* __restrict__ bias,
    ushort* __restrict__ z1t) {
  __shared__ __align__(16) bf16_t as_[64 * 72];           // 9 KB
  __shared__ __align__(16) bf16_t bs_[128 * 72];          // 18 KB
  int b = blockIdx.x >> 4, rt = blockIdx.x & 15;          // grid = 64*16
  int tid = threadIdx.x, wv = tid >> 6, ln = tid & 63;
  const float* xb = x + (size_t)b * 12288;
  #pragma unroll
  for (int it = 0; it < 16; ++it) {
    int e = it * 256 + tid;                               // 4096 A entries
    int p = e >> 6, k = e & 63;
    float v = 0.f;
    if (k < 48) {
      int ci = k >> 4, kh = (k >> 2) & 3, kw = k & 3;
      int row = 2 * rt + (p >> 5); if (row > 30) row = 30; // clamp: discarded
      int col = p & 31;            if (col > 30) col = 30;
      v = xb[ci * 4096 + (2 * row + kh) * 64 + 2 * col + kw];
    }
    as_[p * 72 + k] = (bf16_t)v;
  }
  {
    const float4* wg = (const float4*)wc1;
    #pragma unroll
    for (int it = 0; it < 4; ++it) {
      int fi = it * 256 + tid;                            // 1024 f4s
      int co = fi >> 3, k8 = fi & 7;
      *(float4*)&bs_[co * 72 + k8 * 8] = wg[fi];
    }
  }
  __syncthreads();
  int q = ln >> 4, l = ln & 15;
  f32x4 acc8[8];
  #pragma unroll
  for (int c = 0; c < 8; ++c) acc8[c] = (f32x4){0.f, 0.f, 0.f, 0.f};
  bf16x8 af[2];
  #pragma unroll
  for (int kk = 0; kk < 2; ++kk)
    af[kk] = *(const bf16x8*)&as_[(wv * 16 + l) * 72 + kk * 32 + q * 8];
  #pragma unroll
  for (int cot = 0; cot < 8; ++cot) {
    #pragma unroll
    for (int kk = 0; kk < 2; ++kk) {
      bf16x8 bf = *(const bf16x8*)&bs_[(cot * 16 + l) * 72 + kk * 32 + q * 8];
      acc8[cot] = __builtin_amdgcn_mfma_f32_16x16x32_bf16(af[kk], bf,
                                                          acc8[cot], 0, 0, 0);
    }
  }
  #pragma unroll
  for (int cot = 0; cot < 8; ++cot) {
    int co = cot * 16 + l;
    float bv = bias[co];
    #pragma unroll
    for (int r = 0; r < 4; ++r) {
      int pos = wv * 16 + q * 4 + r;
      int prow = 2 * rt + (pos >> 5), pcol = pos & 31;
      if (prow < 31 && pcol < 31) {
        float v = fmaxf(acc8[cot][r] + bv, 0.f);
        bf16_t h = (bf16_t)v;
        z1t[((size_t)(b * 1024 + prow * 32 + pcol)) * 128 + co] = *(ushort*)&h;
      }
    }
  }
}

// ---------------- conv2 (MFMA, B in LDS): z1t -> relu -> zbuf bf16 only -----
__global__ __launch_bounds__(256, 2) void conv2m_k(const bf16_t* __restrict__ z1t,
    const bf16_t* __restrict__ wc2, const float* __restrict__ bias,
    ushort* __restrict__ zbuf) {
  __shared__ __align__(16) bf16_t as_[98 * 136];          // rows m+off, off<=33
  __shared__ __align__(16) bf16_t bs_[128 * 136];
  int blk = blockIdx.x;                                   // 64*15
  int b = blk / 15, rt = blk % 15;
  int tid = threadIdx.x, wv = tid >> 6, ln = tid & 63;
  const float4* src = (const float4*)(z1t + ((size_t)b * 1024 + rt * 64) * 128);
  #pragma unroll
  for (int s = 0; s < 7; ++s) {
    int f = s * 256 + tid;                                // 98*16 = 1568 f4s
    if (f < 1568) {
      int lp = f >> 4, c16 = f & 15;                      // max row 993 < 1024
      *(float4*)&as_[lp * 136 + c16 * 8] = src[f];
    }
  }
  int m = wv * 16 + (ln & 15), q = ln >> 4;
  f32x4 acc8[8];
  #pragma unroll
  for (int c = 0; c < 8; ++c) acc8[c] = (f32x4){0.f, 0.f, 0.f, 0.f};
  const float4* w4 = (const float4*)wc2;
  #pragma unroll
  for (int t = 0; t < 4; ++t) {
    __syncthreads();                                      // bs_ reuse (+A 1st)
    #pragma unroll
    for (int s = 0; s < 8; ++s) {
      int f = s * 256 + tid;                              // 2048 f4s
      int co = f >> 4, c16 = f & 15;
      *(float4*)&bs_[co * 136 + c16 * 8] = w4[t * 2048 + f];
    }
    __syncthreads();
    int off = (t >> 1) * 32 + (t & 1);                    // tap offset in pos
    bf16x8 af[4];
    #pragma unroll
    for (int kk = 0; kk < 4; ++kk)
      af[kk] = *(const bf16x8*)&as_[(m + off) * 136 + kk * 32 + q * 8];
    #pragma unroll
    for (int cot = 0; cot < 8; ++cot) {
      #pragma unroll
      for (int kk = 0; kk < 4; ++kk) {
        bf16x8 bf = *(const bf16x8*)&bs_[(cot * 16 + (ln & 15)) * 136 +
                                         kk * 32 + q * 8];
        acc8[cot] = __builtin_amdgcn_mfma_f32_16x16x32_bf16(af[kk], bf,
                                                            acc8[cot], 0, 0, 0);
      }
    }
  }
  #pragma unroll
  for (int cot = 0; cot < 8; ++cot) {
    int co = cot * 16 + (ln & 15);
    float bv = bias[co];
    #pragma unroll
    for (int r = 0; r < 4; ++r) {
      int mo = wv * 16 + q * 4 + r;
      int ocol = mo & 31;
      if (ocol < 30) {
        int orow = rt * 2 + (mo >> 5);                    // always < 30
        float v = fmaxf(acc8[cot][r] + bv, 0.f);
        bf16_t h = (bf16_t)v;
        zbuf[(size_t)(b * HID_ + co) * 900 + orow * 30 + ocol] = *(ushort*)&h;
      }
    }
  }
}

// ---------------- VQ phase 1 (MFMA 32x32x16): argmin + hist + fused SSE -----
// r20: 32x32x16 shape — half the LDS b-frag traffic per FLOP vs 16x16x32,
// A-frags (z rows, K=128 = 8 x 16B = 32 VGPR) hoisted out of the chunk loop,
// cn lane-fixed per n-tile. Wave w: mtile=w&1, ntiles {(w>>1)*2, +1}.
// C/D: col(code)=lane&31, row=(reg&3)+8*(reg>>2)+4*(lane>>5)  [m74/m101].
__global__ __launch_bounds__(256, 2) void vq1_k(const bf16_t* __restrict__ zb,
    const bf16_t* __restrict__ cbb, const float* __restrict__ cnorm,
    int* __restrict__ idxArr, unsigned* __restrict__ hist,
    float* __restrict__ sse) {
  __shared__ __align__(16) bf16_t zs[64 * 136];           // 17 KB
  __shared__ __align__(16) bf16_t cbs[128 * 136];         // 34 KB
  __shared__ float cns[K_];                               // 4 KB
  __shared__ unsigned long long red2[128];                // 1 KB
  int n0 = blockIdx.x * 64;                               // 900 blocks
  int tid = threadIdx.x;
  int wv = tid >> 6, ln = tid & 63;
  {
    const float4* zg4 = (const float4*)(zb + (size_t)n0 * HID_);
    #pragma unroll
    for (int s = 0; s < 4; ++s) {
      int f = s * 256 + tid;
      int row = f >> 4, seg = f & 15;
      *(float4*)&zs[row * 136 + seg * 8] = zg4[f];
    }
    ((float4*)cns)[tid] = ((const float4*)cnorm)[tid];    // 1024 floats once
  }
  __syncthreads();
  int mt = wv & 1, npair = wv >> 1;
  int lr = ln & 31, lh = ln >> 5;
  bf16x8 afr[8];                                          // hoisted A (K=128)
  #pragma unroll
  for (int ks = 0; ks < 8; ++ks)
    afr[ks] = *(const bf16x8*)&zs[(mt * 32 + lr) * 136 + ks * 16 + lh * 8];
  unsigned long long best[16];
  #pragma unroll
  for (int r = 0; r < 16; ++r) best[r] = ~0ull;
  const float4* cg4 = (const float4*)cbb;
  for (int c0 = 0; c0 < K_; c0 += 128) {
    __syncthreads();                                      // cbs reuse
    #pragma unroll
    for (int s = 0; s < 8; ++s) {
      int f = s * 256 + tid;
      int code = f >> 4, seg = f & 15;
      *(float4*)&cbs[code * 136 + seg * 8] = cg4[(c0 + code) * 16 + seg];
    }
    __syncthreads();
    #pragma unroll
    for (int nt2 = 0; nt2 < 2; ++nt2) {
      int nt = npair * 2 + nt2;
      f32x16 acc = {0.f, 0.f, 0.f, 0.f, 0.f, 0.f, 0.f, 0.f,
                    0.f, 0.f, 0.f, 0.f, 0.f, 0.f, 0.f, 0.f};
      #pragma unroll
      for (int ks = 0; ks < 8; ++ks) {
        bf16x8 bfr = *(const bf16x8*)&cbs[(nt * 32 + lr) * 136 +
                                          ks * 16 + lh * 8];
        acc = __builtin_amdgcn_mfma_f32_32x32x16_bf16(afr[ks], bfr, acc,
                                                      0, 0, 0);
      }
      int code = c0 + nt * 32 + lr;                       // lane-fixed
      float cn = cns[code];
      unsigned long long lc = (unsigned)code;
      #pragma unroll
      for (int r = 0; r < 16; ++r) {
        float dist = cn - 2.f * acc[r];
        unsigned u = __float_as_uint(dist);
        u = (u & 0x80000000u) ? ~u : (u | 0x80000000u);   // monotone map
        unsigned long long p = ((unsigned long long)u << 32) | lc;
        if (p < best[r]) best[r] = p;                     // tie -> smaller k
      }
    }
  }
  // reduce across the 32 lanes of each half (codes); rows stay per-lane
  #pragma unroll
  for (int r = 0; r < 16; ++r) {
    unsigned long long b = best[r];
    #pragma unroll
    for (int o = 16; o > 0; o >>= 1) {
      unsigned long long ob = __shfl_xor(b, o, 64);
      if (ob < b) b = ob;
    }
    best[r] = b;
  }
  if (lr == 0) {
    #pragma unroll
    for (int r = 0; r < 16; ++r)
      red2[((mt * 2 + npair) * 2 + lh) * 16 + r] = best[r];
  }
  __syncthreads();
  if (tid < 64) {                                         // row = tid
    int fmt = tid >> 5, r32 = tid & 31;
    int half = (r32 >> 2) & 1;
    int reg = (r32 & 3) | (((r32 >> 3) & 3) << 2);
    unsigned long long b0 = red2[((fmt * 2 + 0) * 2 + half) * 16 + reg];
    unsigned long long b1 = red2[((fmt * 2 + 1) * 2 + half) * 16 + reg];
    unsigned long long b = (b1 < b0) ? b1 : b0;
    int bi = (int)(b & 0xffffffffu);
    idxArr[n0 + tid] = bi;
    atomicAdd(&hist[bi], 1u);
    // fused SSE: unmap dmin, add |z'|^2 (row tid in zs)
    unsigned hi = (unsigned)(b >> 32);
    unsigned orig = (hi & 0x80000000u) ? (hi & 0x7fffffffu) : ~hi;
    float dmin = __uint_as_float(orig);
    float zn = 0.f;
    #pragma unroll
    for (int s = 0; s < 16; ++s) {
      bf16x8 v = *(const bf16x8*)&zs[tid * 136 + s * 8];
      #pragma unroll
      for (int e = 0; e < 8; ++e) {
        float fv = (float)v[e];
        zn = fmaf(fv, fv, zn);
      }
    }
    float se = zn + dmin;
    #pragma unroll
    for (int o = 32; o > 0; o >>= 1) se += __shfl_down(se, o, 64);
    if (tid == 0) atomicAdd(sse, se);
  }
}

// ---------------- tqz: tq gather + qt pad zero ------------------------------
__global__ __launch_bounds__(256) void tqz_k(const bf16_t* __restrict__ cbb,
    const int* __restrict__ idxArr, ushort* __restrict__ qt) {
  __shared__ ushort t[60 * 128];                          // 15 KB
  int bid = blockIdx.x, tid = threadIdx.x;
  if (bid < 960) {                                        // ---- tq ----
    int b = bid / 15, st = bid % 15;                      // 60-s tile
    int s0 = st * 60;
    #pragma unroll
    for (int it = 0; it < 8; ++it) {
      int task = it * 256 + tid;                          // sc*128 + c
      if (task < 1920) {
        int sc = task >> 7, c = task & 127;
        int f = b * 115200 + c * 900 + s0 + sc * 4;
        int n = f >> 7, d = f & 127;                      // d%4==0, no wrap
        int k = idxArr[n];
        ushort4 v = *(const ushort4*)((const ushort*)cbb + k * 128 + d);
        t[(sc * 4 + 0) * 128 + c] = v.x;
        t[(sc * 4 + 1) * 128 + c] = v.y;
        t[(sc * 4 + 2) * 128 + c] = v.z;
        t[(sc * 4 + 3) * 128 + c] = v.w;
      }
    }
    __syncthreads();
    #pragma unroll
    for (int it = 0; it < 4; ++it) {
      int task = it * 256 + tid;                          // sl*16 + c16
      if (task < 960) {
        int sl = task >> 4, c16 = task & 15;
        int s = s0 + sl;
        int h = s / 30, w = s - h * 30;
        int p = (h + 1) * 32 + (w + 1);
        *(uint4*)&qt[((size_t)(b * 1024 + p)) * 128 + c16 * 8] =
            *(uint4*)&t[sl * 128 + c16 * 8];
      }
    }
  } else {                                                // ---- qt pad ----
    int zb_ = (bid - 960) * 4;                            // 4 b's per block
    uint4 zz = {0u, 0u, 0u, 0u};
    for (int e = tid; e < 4 * 124 * 16; e += 256) {
      int bb = zb_ + e / (124 * 16);
      int rem = e % (124 * 16);
      int pe = rem >> 4, s16 = rem & 15;
      int p;
      if (pe < 32) p = pe;                                // row 0
      else if (pe < 64) p = 31 * 32 + (pe - 32);          // row 31
      else {
        int idx = pe - 64;                                // rows 1..30, c 0/31
        p = (1 + (idx >> 1)) * 32 + ((idx & 1) ? 31 : 0);
      }
      *(uint4*)&qt[((size_t)(bb * 1024 + p)) * 128 + s16 * 8] = zz;
    }
  }
}

// ---------------- convT1 (MFMA, B in LDS): qt -> relu -> yt bf16 ------------
__global__ __launch_bounds__(256, 2) void convt1m_k(const bf16_t* __restrict__ qt,
    const bf16_t* __restrict__ wd1, const float* __restrict__ bias,
    ushort* __restrict__ yt) {
  __shared__ __align__(16) bf16_t as_[98 * 136];
  __shared__ __align__(16) bf16_t bs_[128 * 136];
  int blk = blockIdx.x;                                   // 64*16
  int b = blk >> 4, rt = blk & 15;
  int tid = threadIdx.x, wv = tid >> 6, ln = tid & 63;
  {                                                       // fused pad zeroing
    uint4 zz = {0u, 0u, 0u, 0u};
    ushort* ytb = yt + (size_t)b * 1156 * 128;
    int nrows = (rt < 15) ? 2 : 1;                        // rt=15 owns row 31
    int r0 = 2 * rt + 1;
    for (int e = tid; e < nrows * 48; e += 256) {         // cols 0,32,33
      int rr = e / 48, rem = e % 48, cc = rem / 16, s16 = rem % 16;
      int col = (cc == 0) ? 0 : (cc == 1 ? 32 : 33);
      *(uint4*)&ytb[((size_t)((r0 + rr) * 34 + col)) * 128 + s16 * 8] = zz;
    }
    if (rt == 0)
      for (int e = tid; e < 34 * 16; e += 256)            // row 0
        *(uint4*)&ytb[((size_t)(e >> 4)) * 128 + (e & 15) * 8] = zz;
    if (rt == 15)
      for (int e = tid; e < 2 * 34 * 16; e += 256) {      // rows 32,33
        int rr = 32 + e / 544, rem = e % 544;
        *(uint4*)&ytb[((size_t)(rr * 34 + (rem >> 4))) * 128 + (rem & 15) * 8]
            = zz;
      }
  }
  const float4* src = (const float4*)(qt + (size_t)b * 1024 * 128);
  #pragma unroll
  for (int s = 0; s < 7; ++s) {
    int f = s * 256 + tid;                                // 1568 f4s
    if (f < 1568) {
      int lp = f >> 4, c16 = f & 15;
      int gr = rt * 64 + lp;
      if (gr > 1023) gr = 1023;                           // rt=15 guard
      *(float4*)&as_[lp * 136 + c16 * 8] = src[gr * 16 + c16];
    }
  }
  int m = wv * 16 + (ln & 15), q = ln >> 4;
  f32x4 acc8[8];
  #pragma unroll
  for (int c = 0; c < 8; ++c) acc8[c] = (f32x4){0.f, 0.f, 0.f, 0.f};
  const float4* w4 = (const float4*)wd1;
  #pragma unroll
  for (int t = 0; t < 4; ++t) {
    __syncthreads();
    #pragma unroll
    for (int s = 0; s < 8; ++s) {
      int f = s * 256 + tid;
      int co = f >> 4, c16 = f & 15;
      *(float4*)&bs_[co * 136 + c16 * 8] = w4[t * 2048 + f];
    }
    __syncthreads();
    int off = (t >> 1) * 32 + (t & 1);
    bf16x8 af[4];
    #pragma unroll
    for (int kk = 0; kk < 4; ++kk)
      af[kk] = *(const bf16x8*)&as_[(m + off) * 136 + kk * 32 + q * 8];
    #pragma unroll
    for (int cot = 0; cot < 8; ++cot) {
      #pragma unroll
      for (int kk = 0; kk < 4; ++kk) {
        bf16x8 bf = *(const bf16x8*)&bs_[(cot * 16 + (ln & 15)) * 136 +
                                         kk * 32 + q * 8];
        acc8[cot] = __builtin_amdgcn_mfma_f32_16x16x32_bf16(af[kk], bf,
                                                            acc8[cot], 0, 0, 0);
      }
    }
  }
  #pragma unroll
  for (int cot = 0; cot < 8; ++cot) {
    int co = cot * 16 + (ln & 15);
    float bv = bias[co];
    #pragma unroll
    for (int r = 0; r < 4; ++r) {
      int mo = wv * 16 + q * 4 + r;
      int orow = rt * 2 + (mo >> 5), ocol = mo & 31;
      if (orow < 31 && ocol < 31) {
        float v = fmaxf(acc8[cot][r] + bv, 0.f);
        bf16_t h = (bf16_t)v;
        yt[((size_t)b * 1156 + (orow + 1) * 34 + (ocol + 1)) * 128 + co] =
            *(ushort*)&h;
      }
    }
  }
}

// ---------------- convT2 (MFMA): yt -> out fp32, + fused finalize -----------
__global__ __launch_bounds__(256, 2) void convt2m_k(const bf16_t* __restrict__ yt,
    const bf16_t* __restrict__ wt2, const float* __restrict__ bias,
    const unsigned* __restrict__ hist, const float* __restrict__ sse,
    float* __restrict__ out) {
  __shared__ __align__(16) bf16_t as_[128 * 136];         // 34.8 KB
  __shared__ float redf[256];                             // 1 KB (fin branch)
  int b = blockIdx.x >> 4, rt = blockIdx.x & 15;          // grid = 64*16
  int tid = threadIdx.x, wv = tid >> 6, ln = tid & 63;
  const float4* src = (const float4*)(yt + ((size_t)b * 1156 + rt * 68) * 128);
  #pragma unroll
  for (int s = 0; s < 8; ++s) {
    int f = s * 256 + tid;
    int lp = f >> 4, c16 = f & 15;
    *(float4*)&as_[lp * 136 + c16 * 8] = src[f];
  }
  __syncthreads();
  int mloc = wv * 16 + (ln & 15), q = ln >> 4;
  int qh = mloc >> 5, qw = mloc & 31;                     // local quadrant pos
  int base = (qh + 1) * 34 + qw + 1;                      // in staged window
  f32x4 acc = {0.f, 0.f, 0.f, 0.f};
  #pragma unroll
  for (int kc = 0; kc < 16; ++kc) {
    int tap = kc >> 2;
    int toff = (tap & 1) + (tap >> 1) * 34;               // 0,1,34,35
    bf16x8 af = *(const bf16x8*)&as_[(base - toff) * 136 +
                                     (kc & 3) * 32 + q * 8];
    bf16x8 bf = *(const bf16x8*)&wt2[(size_t)(ln & 15) * 512 + kc * 32 + q * 8];
    acc = __builtin_amdgcn_mfma_f32_16x16x32_bf16(af, bf, acc, 0, 0, 0);
  }
  __syncthreads();                                        // as_ reads done
  float* bb = (float*)as_;                                // bounce: 64x16 f32
  #pragma unroll
  for (int r = 0; r < 4; ++r)
    bb[(wv * 16 + q * 4 + r) * 16 + (ln & 15)] = acc[r];
  __syncthreads();
  if (tid < 192) {
    int row_id = tid >> 4;                                // co*4 + ohoff
    int co = row_id >> 2, ohoff = row_id & 3;
    int qhl = ohoff >> 1, ph = ohoff & 1;
    float bv = bias[co];
    int ow0 = (tid & 15) * 4;
    float tmp[4];
    #pragma unroll
    for (int e = 0; e < 4; ++e) {
      int ow = ow0 + e;
      tmp[e] = bb[(qhl * 32 + (ow >> 1)) * 16 + co * 4 + ph * 2 + (ow & 1)]
               + bv;
    }
    *(float4*)&out[((size_t)(b * 3 + co)) * 4096 + (rt * 4 + ohoff) * 64 + ow0]
        = *(float4*)tmp;
  }
  if (blockIdx.x == 0) {                                  // ---- fused fin ----
    float e = 0.f;
    for (int k = tid; k < K_; k += 256) {
      float p = (float)hist[k] * (1.0f / (float)NROWS_);
      e += p * logf(p + 1e-10f);
    }
    redf[tid] = e;
    __syncthreads();
    #pragma unroll
    for (int t = 128; t > 0; t >>= 1) {
      if (tid < t) redf[tid] += redf[tid + t];
      __syncthreads();
    }
    if (tid == 0) {
      out[786432] = 1.25f * (*sse) * (1.0f / (float)NELEM_);
      out[786433] = expf(-redf[0]);
    }
  }
}

extern "C" void kernel_launch(void* const* d_in, const int* in_sizes, int n_in,
                              void* d_out, int out_size, void* d_ws,
                              size_t ws_size, hipStream_t stream) {
  (void)in_sizes; (void)n_in; (void)out_size; (void)ws_size;
  const float* x   = (const float*)d_in[0];
  const float* ew1 = (const float*)d_in[1];
  const float* eb1 = (const float*)d_in[2];
  const float* ew2 = (const float*)d_in[3];
  const float* eb2 = (const float*)d_in[4];
  const float* cb  = (const float*)d_in[5];
  const float* dw1 = (const float*)d_in[6];
  const float* db1 = (const float*)d_in[7];
  const float* dw2 = (const float*)d_in[8];
  const float* db2 = (const float*)d_in[9];
  float* out = (float*)d_out;
  char* ws = (char*)d_ws;

  // ws layout (~97.5 MB, aliased by liveness):
  //  [0, 35,684,352)            yt bf16 18.94 MB (pad zeroed in convt1m)
  //  [65,175,552, 81,985,536)   z1t bf16 (conv1m->conv2m) then qt bf16
  //  [81,985,536, 96,731,136)   zbuf bf16 (conv2m->vq1)
  //  [96,731,136 ..)  cbb | wc2 | wd1 | idxArr | hist | cnorm | sse | wt2 | wc1
  ushort*   yt    = (ushort*)(ws);
  bf16_t*   z1t   = (bf16_t*)(ws + 65175552);
  bf16_t*   qt    = (bf16_t*)(ws + 65175552);
  ushort*   zbuf  = (ushort*)(ws + 81985536);
  bf16_t*   cbb   = (bf16_t*)(ws + 96731136);
  bf16_t*   wc2   = (bf16_t*)(ws + 96993280);
  bf16_t*   wd1   = (bf16_t*)(ws + 97124352);
  int*      idxArr= (int*)(ws + 97255424);
  unsigned* hist  = (unsigned*)(ws + 97485824);
  float*    cnorm = (float*)(ws + 97489920);
  float*    sse   = (float*)(ws + 97494016);
  bf16_t*   wt2   = (bf16_t*)(ws + 97497088);
  bf16_t*   wc1   = (bf16_t*)(ws + 97513472);

  wprep_k<<<dim3(256), dim3(256), 0, stream>>>(ew1, ew2, dw1, dw2, cb,
                                               wc1, wc2, wd1, wt2,
                                               cbb, cnorm, hist, sse);
  conv1m_k<<<dim3(1024), dim3(256), 0, stream>>>(x, wc1, eb1, (ushort*)z1t);
  conv2m_k<<<dim3(960), dim3(256), 0, stream>>>(z1t, wc2, eb2, zbuf);
  vq1_k<<<dim3(900), dim3(256), 0, stream>>>((const bf16_t*)zbuf, cbb, cnorm,
                                             idxArr, hist, sse);
  tqz_k<<<dim3(976), dim3(256), 0, stream>>>(cbb, idxArr, (ushort*)qt);
  convt1m_k<<<dim3(1024), dim3(256), 0, stream>>>(qt, wd1, db1, yt);
  convt2m_k<<<dim3(1024), dim3(256), 0, stream>>>((const bf16_t*)yt, wt2, db2,
                                                  hist, sse, out);
}